// Round 16
// baseline (905.777 us; speedup 1.0000x reference)
//
#include <hip/hip_runtime.h>

#define HW 65536
#define NC 12
#define NF 64
#define NT 8
#define P2 260   // padded pitch (2-wide zero border each side)

typedef float2 c32;
typedef __attribute__((ext_vector_type(8))) short bf16x8;   // 8 bf16 = 4 VGPR
typedef __attribute__((ext_vector_type(4))) float f32x4;    // MFMA C/D

__device__ __forceinline__ float ssign(int p) {
    return ((p ^ (p >> 8)) & 1) ? -1.0f : 1.0f;
}

__device__ __forceinline__ short f2bf(float f) {   // RNE float->bf16
    union { float f; unsigned u; } v; v.f = f;
    unsigned r = (v.u + 0x7FFFu + ((v.u >> 16) & 1u)) >> 16;
    return (short)r;
}

__device__ __forceinline__ float bf2f(unsigned short u) {
    union { unsigned u; float f; } v; v.u = (unsigned)u << 16;
    return v.f;
}

// ===================== 256-point FFT, wave-synchronous, fused stage-pairs ===
__device__ __forceinline__ void wave_sync() {
    asm volatile("s_waitcnt lgkmcnt(0)" ::: "memory");
}

__device__ __forceinline__ void fft256_wave(c32* X, const c32* tw, int j, float conjf) {
    #pragma unroll
    for (int s = 1; s <= 8; s += 2) {
        const int H = 1 << (s - 1);
        int p = j & (H - 1);
        int r = j >> (s - 1);
        int i0 = r * 4 * H + p;
        c32 e0 = X[i0], e1 = X[i0 + H], e2 = X[i0 + 2 * H], e3 = X[i0 + 3 * H];
        c32 w = tw[p << (8 - s)];
        float wy = conjf * w.y;
        c32 t = make_float2(w.x * e1.x - wy * e1.y, w.x * e1.y + wy * e1.x);
        c32 a0 = make_float2(e0.x + t.x, e0.y + t.y);
        c32 a1 = make_float2(e0.x - t.x, e0.y - t.y);
        t = make_float2(w.x * e3.x - wy * e3.y, w.x * e3.y + wy * e3.x);
        c32 a2 = make_float2(e2.x + t.x, e2.y + t.y);
        c32 a3 = make_float2(e2.x - t.x, e2.y - t.y);
        c32 w0 = tw[p << (7 - s)];
        c32 w1 = tw[(p + H) << (7 - s)];
        float w0y = conjf * w0.y, w1y = conjf * w1.y;
        t = make_float2(w0.x * a2.x - w0y * a2.y, w0.x * a2.y + w0y * a2.x);
        X[i0]         = make_float2(a0.x + t.x, a0.y + t.y);
        X[i0 + 2 * H] = make_float2(a0.x - t.x, a0.y - t.y);
        t = make_float2(w1.x * a3.x - w1y * a3.y, w1.x * a3.y + w1y * a3.x);
        X[i0 + H]     = make_float2(a1.x + t.x, a1.y + t.y);
        X[i0 + 3 * H] = make_float2(a1.x - t.x, a1.y - t.y);
        wave_sync();
    }
}

__device__ __forceinline__ void build_tw(c32* tw, int tid) {
    if (tid < 128) {
        float a = -3.14159265358979323846f * (float)tid * (1.0f / 128.0f);
        float sv, cv;
        sincosf(a, &sv, &cv);
        tw[tid] = make_float2(cv, sv);
    }
}

__global__ __launch_bounds__(256) void fft_rows_pre(c32* __restrict__ buf,
        const c32* __restrict__ pred) {
    __shared__ c32 lds[4][256];
    __shared__ c32 tw[128];
    int tid = threadIdx.x;
    build_tw(tw, tid);
    int wid = tid >> 6, j = tid & 63;
    int r = blockIdx.x * 4 + wid;
    int coil = r >> 8, y = r & 255;
    c32* rp = buf + (size_t)r * 256;
    c32* X = lds[wid];
    #pragma unroll
    for (int e = 0; e < 4; ++e) {
        int n = (e << 6) + j;
        float s = ((n + y) & 1) ? -1.0f : 1.0f;
        c32 pv = pred[(size_t)coil * HW + y * 256 + n];
        X[__brev((unsigned)n) >> 24] = make_float2(s * pv.x, s * pv.y);
    }
    __syncthreads();
    fft256_wave(X, tw, j, -1.0f);
    #pragma unroll
    for (int e = 0; e < 4; ++e) {
        int n = (e << 6) + j;
        rp[n] = X[n];
    }
}

__global__ __launch_bounds__(256) void fft_rows_exp(c32* __restrict__ buf,
        const c32* __restrict__ eta, const c32* __restrict__ sense) {
    __shared__ c32 lds[4][256];
    __shared__ c32 tw[128];
    int tid = threadIdx.x;
    build_tw(tw, tid);
    int wid = tid >> 6, j = tid & 63;
    int r = blockIdx.x * 4 + wid;
    int coil = r >> 8, y = r & 255;
    c32* rp = buf + (size_t)r * 256;
    c32* X = lds[wid];
    #pragma unroll
    for (int e = 0; e < 4; ++e) {
        int n = (e << 6) + j;
        float s = ((n + y) & 1) ? -1.0f : 1.0f;
        c32 ev = eta[y * 256 + n];
        c32 sn = sense[(size_t)coil * HW + y * 256 + n];
        X[__brev((unsigned)n) >> 24] =
            make_float2(s * (ev.x * sn.x - ev.y * sn.y),
                        s * (ev.x * sn.y + ev.y * sn.x));
    }
    __syncthreads();
    fft256_wave(X, tw, j, 1.0f);
    #pragma unroll
    for (int e = 0; e < 4; ++e) {
        int n = (e << 6) + j;
        rp[n] = X[n];
    }
}

// Merged: row-inverse FFT of all 12 coils of row y + coil-combine + g emit.
__global__ __launch_bounds__(256) void fft_rows_grad(const c32* __restrict__ Fk,
        const c32* __restrict__ sense, const c32* __restrict__ eta,
        short* __restrict__ gTp) {
    __shared__ c32 lds[12][256];     // 24 KB
    __shared__ c32 tw[128];
    int tid = threadIdx.x;
    build_tw(tw, tid);
    int wid = tid >> 6, j = tid & 63;
    int y = blockIdx.x;
    #pragma unroll
    for (int cc = 0; cc < 3; ++cc) {
        int c = wid * 3 + cc;
        const c32* rp = Fk + (size_t)c * HW + y * 256;
        #pragma unroll
        for (int e = 0; e < 4; ++e) {
            int n = (e << 6) + j;
            lds[c][__brev((unsigned)n) >> 24] = rp[n];
        }
    }
    __syncthreads();
    #pragma unroll
    for (int cc = 0; cc < 3; ++cc)
        fft256_wave(&lds[wid * 3 + cc][0], tw, j, -1.0f);
    __syncthreads();
    int x = tid;
    int p = y * 256 + x;
    float ax = 0.f, ay = 0.f;
    #pragma unroll
    for (int c = 0; c < NC; ++c) {
        c32 t = lds[c][x];
        c32 s = sense[(size_t)c * HW + p];
        ax += t.x * s.x + t.y * s.y;
        ay += t.y * s.x - t.x * s.y;
    }
    float sc = (((x + y) & 1) ? -1.0f : 1.0f) * (1.0f / 256.0f);
    c32 e = eta[p];
    ushort4 o;
    o.x = (unsigned short)f2bf(e.x);
    o.y = (unsigned short)f2bf(e.y);
    o.z = (unsigned short)f2bf(ax * sc);
    o.w = (unsigned short)f2bf(ay * sc);
    ((ushort4*)gTp)[(y + 2) * P2 + x + 2] = o;
}

// 8-column col FFT (init inverse only). grid (32, NC), 256 thr, 64B coalesced.
__global__ __launch_bounds__(256) void fft_cols(c32* __restrict__ buf, float conjf) {
    __shared__ c32 lds[8][257];
    __shared__ c32 tw[128];
    int tid = threadIdx.x;
    build_tw(tw, tid);
    c32* ip = buf + (size_t)blockIdx.y * HW;
    int x0 = blockIdx.x * 8;
    int xl = tid & 7, yb = tid >> 3;     // yb in 0..31
    #pragma unroll
    for (int e = 0; e < 8; ++e) {
        int y = yb + (e << 5);
        lds[xl][__brev((unsigned)y) >> 24] = ip[y * 256 + x0 + xl];
    }
    __syncthreads();
    int wv = tid >> 6, j = tid & 63;
    #pragma unroll
    for (int cc = 0; cc < 2; ++cc)
        fft256_wave(&lds[wv * 2 + cc][0], tw, j, conjf);
    __syncthreads();
    #pragma unroll
    for (int e = 0; e < 8; ++e) {
        int y = yb + (e << 5);
        ip[y * 256 + x0 + xl] = lds[xl][y];
    }
}

// 8-column fused: fwd col FFT -> (out write + masked residual) -> inv col FFT.
// grid (32, NC), 256 thr.
__global__ __launch_bounds__(256) void fft_cols_fused(c32* __restrict__ buf,
        const c32* __restrict__ base, const c32* __restrict__ ksp,
        const int* __restrict__ mask, c32* __restrict__ outp, int write_out) {
    __shared__ c32 lds[8][257];
    __shared__ c32 tw[128];
    int tid = threadIdx.x;
    build_tw(tw, tid);
    int coil = blockIdx.y;
    c32* ip = buf + (size_t)coil * HW;
    int x0 = blockIdx.x * 8;
    int xl = tid & 7, yb = tid >> 3;
    #pragma unroll
    for (int e = 0; e < 8; ++e) {
        int y = yb + (e << 5);
        lds[xl][__brev((unsigned)y) >> 24] = ip[y * 256 + x0 + xl];
    }
    __syncthreads();
    int wv = tid >> 6, j = tid & 63;
    #pragma unroll
    for (int cc = 0; cc < 2; ++cc)
        fft256_wave(&lds[wv * 2 + cc][0], tw, j, 1.0f);
    __syncthreads();

    int x = x0 + xl;
    c32 G[8];
    #pragma unroll
    for (int e = 0; e < 8; ++e) {
        int y = yb + (e << 5);
        G[e] = lds[xl][y];
    }
    __syncthreads();
    #pragma unroll
    for (int e = 0; e < 8; ++e) {
        int y = yb + (e << 5);
        int p = y * 256 + x;
        size_t i = (size_t)coil * HW + p;
        float s = ((p ^ (p >> 8)) & 1) ? -1.0f : 1.0f;
        if (write_out) {
            c32 bv = base[i];
            float sc = s * (1.0f / 256.0f);
            outp[i] = make_float2(bv.x - sc * G[e].x, bv.y - sc * G[e].y);
        }
        c32 rv = make_float2(0.f, 0.f);
        if (mask[p]) {
            c32 k = ksp[i];
            rv = make_float2(G[e].x * (1.0f / 256.0f) - s * k.x,
                             G[e].y * (1.0f / 256.0f) - s * k.y);
        }
        lds[xl][__brev((unsigned)y) >> 24] = rv;
    }
    __syncthreads();
    #pragma unroll
    for (int cc = 0; cc < 2; ++cc)
        fft256_wave(&lds[wv * 2 + cc][0], tw, j, -1.0f);
    __syncthreads();
    #pragma unroll
    for (int e = 0; e < 8; ++e) {
        int y = yb + (e << 5);
        ip[y * 256 + x0 + xl] = lds[xl][y];
    }
}

// ===================== pointwise kernels =====================
__global__ __launch_bounds__(256) void k_combine_eta0(const c32* __restrict__ tmp,
        const c32* __restrict__ sense, c32* __restrict__ eta) {
    int p = blockIdx.x * 256 + threadIdx.x;
    float ax = 0.f, ay = 0.f;
    for (int c = 0; c < NC; ++c) {
        c32 t = tmp[c * HW + p], s = sense[c * HW + p];
        ax += t.x * s.x + t.y * s.y;
        ay += t.y * s.x - t.x * s.y;
    }
    float sc = ssign(p) * (1.0f / 256.0f);
    eta[p] = make_float2(ax * sc, ay * sc);
}

__global__ __launch_bounds__(256) void k_base(const c32* __restrict__ ksp,
        const c32* __restrict__ pred, const int* __restrict__ mask,
        const float* __restrict__ dcw, c32* __restrict__ base) {
    int i = blockIdx.x * 256 + threadIdx.x;
    int p = i & (HW - 1);
    c32 k = ksp[i];
    c32 o = k;
    if (mask[p]) {
        float w = dcw[0];
        c32 pr = pred[i];
        o.x -= (pr.x - k.x) * w;
        o.y -= (pr.y - k.y) * w;
    }
    base[i] = o;
}

// Zero the border pixels of gTp + the 4 padded h buffers.
__global__ __launch_bounds__(256) void k_zero_border(short* __restrict__ gTp,
        short* __restrict__ h1a, short* __restrict__ h1b,
        short* __restrict__ h2a, short* __restrict__ h2b) {
    int i = blockIdx.x * 256 + threadIdx.x;
    if (i >= 2064) return;
    int y, x;
    if (i < 1040) {
        int r = i / 260;
        y = (r < 2) ? r : 256 + r;
        x = i % 260;
    } else {
        int j = i - 1040;
        y = 2 + (j >> 2);
        int cix = j & 3;
        x = (cix < 2) ? cix : 256 + cix;
    }
    size_t px = (size_t)y * P2 + x;
    ((ushort4*)gTp)[px] = make_ushort4(0, 0, 0, 0);
    uint4 z = make_uint4(0, 0, 0, 0);
    uint4* p1 = (uint4*)(h1a + (px << 6));
    uint4* p2 = (uint4*)(h1b + (px << 6));
    uint4* p3 = (uint4*)(h2a + (px << 6));
    uint4* p4 = (uint4*)(h2b + (px << 6));
    #pragma unroll
    for (int e = 0; e < 8; ++e) { p1[e] = z; p2[e] = z; p3[e] = z; p4[e] = z; }
}

// ===================== weight prep kernels =====================
__global__ __launch_bounds__(256) void k_prep_c1(const float* __restrict__ w,
        short* __restrict__ wA) {
    int i = blockIdx.x * 256 + threadIdx.x;    // 64*128
    int co = i >> 7, k = i & 127;
    int tap = k >> 2, ci = k & 3;
    float v = (tap < 25) ? w[co * 100 + ci * 25 + tap] : 0.f;
    wA[i] = f2bf(v);
}

__global__ __launch_bounds__(256) void k_prep_c2(const float* __restrict__ w,
        short* __restrict__ wA) {
    int i = blockIdx.x * 256 + threadIdx.x;     // 36864
    int tap = i >> 12, co = (i >> 6) & 63, ci = i & 63;
    wA[i] = f2bf(w[co * 576 + ci * 9 + tap]);
}

__global__ __launch_bounds__(256) void k_prep_cf(const float* __restrict__ w,
        short* __restrict__ wA) {
    int i = blockIdx.x * 256 + threadIdx.x;    // 9216
    int tap = i >> 10, r = (i >> 6) & 15, ci = i & 63;
    float v = (r < 2) ? w[r * 576 + ci * 9 + tap] : 0.f;
    wA[i] = f2bf(v);
}

__global__ __launch_bounds__(128) void k_prep_gru(const float* __restrict__ ihw,
        const float* __restrict__ ihb, const float* __restrict__ hhw,
        const float* __restrict__ hhb, short* __restrict__ w2, float* __restrict__ bias) {
    int k = threadIdx.x;
    int r = blockIdx.x;
    int g = r >> 6, co = r & 63;
    float v = 0.f;
    if (g == 0)      v = (k < 64) ? ihw[co * 64 + k]         : hhw[co * 64 + k - 64];
    else if (g == 1) v = (k < 64) ? ihw[(64 + co) * 64 + k]  : hhw[(64 + co) * 64 + k - 64];
    else if (g == 2) v = (k < 64) ? ihw[(128 + co) * 64 + k] : 0.f;
    else             v = (k < 64) ? 0.f : hhw[(128 + co) * 64 + k - 64];
    w2[r * 128 + k] = f2bf(v);
    if (k == 0) {
        float b = (g == 0) ? ihb[co] + hhb[co]
                : (g == 1) ? ihb[64 + co] + hhb[64 + co]
                : (g == 2) ? ihb[128 + co] : hhb[128 + co];
        bias[r] = b;
    }
}

// ===================== shared GRU tail (x from LDS, h from global) =========
template <int NTN, bool FIRST>
__device__ __forceinline__ void gru_tail(const short (*xch)[68],
        const short* __restrict__ hprev, const short* __restrict__ w2,
        const float* __restrict__ bias, short* __restrict__ hnext,
        int wv, int lr, int lg, int px0) {
    bf16x8 A0[4], A1[4], A2[2], A3[2];
    {
        const short* w0 = w2 + (0   + wv * 16 + lr) * 128 + lg * 8;
        const short* w1 = w2 + (64  + wv * 16 + lr) * 128 + lg * 8;
        const short* w2p = w2 + (128 + wv * 16 + lr) * 128 + lg * 8;
        const short* w3 = w2 + (192 + wv * 16 + lr) * 128 + lg * 8;
        #pragma unroll
        for (int kt = 0; kt < 4; ++kt) {
            A0[kt] = *(const bf16x8*)(w0 + kt * 32);
            A1[kt] = *(const bf16x8*)(w1 + kt * 32);
        }
        A2[0] = *(const bf16x8*)(w2p);          A2[1] = *(const bf16x8*)(w2p + 32);
        A3[0] = *(const bf16x8*)(w3 + 64);      A3[1] = *(const bf16x8*)(w3 + 96);
    }

    f32x4 C0[NTN], C1[NTN], C2[NTN], C3[NTN];
    #pragma unroll
    for (int nt = 0; nt < NTN; ++nt) {
        C0[nt] = (f32x4){0.f, 0.f, 0.f, 0.f};
        C1[nt] = (f32x4){0.f, 0.f, 0.f, 0.f};
        C2[nt] = (f32x4){0.f, 0.f, 0.f, 0.f};
        C3[nt] = (f32x4){0.f, 0.f, 0.f, 0.f};
    }

    #pragma unroll
    for (int nt = 0; nt < NTN; ++nt) {
        int pxl = nt * 16 + lr;
        int px = px0 + pxl;
        int yy = px >> 8, xx = px & 255;
        size_t pb = ((size_t)((yy + 2) * P2 + (xx + 2)) << 6);
        bf16x8 B0 = *(const bf16x8*)&xch[pxl][lg * 8];
        bf16x8 B1 = *(const bf16x8*)&xch[pxl][32 + lg * 8];
        C0[nt] = __builtin_amdgcn_mfma_f32_16x16x32_bf16(A0[0], B0, C0[nt], 0, 0, 0);
        C0[nt] = __builtin_amdgcn_mfma_f32_16x16x32_bf16(A0[1], B1, C0[nt], 0, 0, 0);
        C1[nt] = __builtin_amdgcn_mfma_f32_16x16x32_bf16(A1[0], B0, C1[nt], 0, 0, 0);
        C1[nt] = __builtin_amdgcn_mfma_f32_16x16x32_bf16(A1[1], B1, C1[nt], 0, 0, 0);
        C2[nt] = __builtin_amdgcn_mfma_f32_16x16x32_bf16(A2[0], B0, C2[nt], 0, 0, 0);
        C2[nt] = __builtin_amdgcn_mfma_f32_16x16x32_bf16(A2[1], B1, C2[nt], 0, 0, 0);
        if (!FIRST) {
            bf16x8 B2 = *(const bf16x8*)(hprev + pb + lg * 8);
            bf16x8 B3 = *(const bf16x8*)(hprev + pb + 32 + lg * 8);
            C0[nt] = __builtin_amdgcn_mfma_f32_16x16x32_bf16(A0[2], B2, C0[nt], 0, 0, 0);
            C0[nt] = __builtin_amdgcn_mfma_f32_16x16x32_bf16(A0[3], B3, C0[nt], 0, 0, 0);
            C1[nt] = __builtin_amdgcn_mfma_f32_16x16x32_bf16(A1[2], B2, C1[nt], 0, 0, 0);
            C1[nt] = __builtin_amdgcn_mfma_f32_16x16x32_bf16(A1[3], B3, C1[nt], 0, 0, 0);
            C3[nt] = __builtin_amdgcn_mfma_f32_16x16x32_bf16(A3[0], B2, C3[nt], 0, 0, 0);
            C3[nt] = __builtin_amdgcn_mfma_f32_16x16x32_bf16(A3[1], B3, C3[nt], 0, 0, 0);
        }
    }

    int co = wv * 16 + lg * 4;
    float br[4], bz[4], bin_[4], bhn[4];
    #pragma unroll
    for (int i = 0; i < 4; ++i) {
        br[i]   = bias[co + i];
        bz[i]   = bias[64 + co + i];
        bin_[i] = bias[128 + co + i];
        bhn[i]  = bias[192 + co + i];
    }
    #pragma unroll
    for (int nt = 0; nt < NTN; ++nt) {
        int px = px0 + nt * 16 + lr;
        int yy = px >> 8, xx = px & 255;
        size_t pb = ((size_t)((yy + 2) * P2 + (xx + 2)) << 6);
        ushort4 hov = make_ushort4(0, 0, 0, 0);
        if (!FIRST) hov = *(const ushort4*)(hprev + pb + co);
        float ho[4] = {bf2f(hov.x), bf2f(hov.y), bf2f(hov.z), bf2f(hov.w)};
        ushort4 st;
        unsigned short* sp = &st.x;
        #pragma unroll
        for (int i = 0; i < 4; ++i) {
            float r = 1.0f / (1.0f + expf(-(C0[nt][i] + br[i])));
            float z = 1.0f / (1.0f + expf(-(C1[nt][i] + bz[i])));
            float nn = tanhf(C2[nt][i] + bin_[i] + r * (C3[nt][i] + bhn[i]));
            float hv = FIRST ? (1.0f - z) * nn : (1.0f - z) * nn + z * ho[i];
            sp[i] = (unsigned short)f2bf(hv);
        }
        *(ushort4*)(hnext + pb + co) = st;
    }
}

// ===================== conv1 + gru1 fused =====================
template <bool FIRST>
__global__ __launch_bounds__(256, 2) void conv1_gru1(const short* __restrict__ gTp,
        const short* __restrict__ wA, const float* __restrict__ cbias,
        const short* __restrict__ w2, const float* __restrict__ gbias,
        const short* __restrict__ hprev, short* __restrict__ hnext) {
    __shared__ short xch[32][68];
    int wv = threadIdx.x >> 6, l = threadIdx.x & 63;
    int lr = l & 15, lg = l >> 4;
    int y = blockIdx.x >> 3;
    int x0 = (blockIdx.x & 7) << 5;

    bf16x8 A[4];
    const short* pA = wA + (size_t)(wv * 16 + lr) * 128 + lg * 8;
    #pragma unroll
    for (int kt = 0; kt < 4; ++kt) A[kt] = *(const bf16x8*)(pA + kt * 32);

    bf16x8 B[2][4];
    #pragma unroll
    for (int nt = 0; nt < 2; ++nt) {
        int x = x0 + nt * 16 + lr;
        #pragma unroll
        for (int kt = 0; kt < 4; ++kt) {
            int t0 = kt * 8 + lg * 2;
            #pragma unroll
            for (int half = 0; half < 2; ++half) {
                int tap = t0 + half;
                int tt = (tap < 25) ? tap : 0;
                int dy = tt / 5 - 2, dx = tt % 5 - 2;
                ushort4 v = *(const ushort4*)(gTp +
                    ((size_t)((y + dy + 2) * P2 + (x + dx + 2)) << 2));
                B[nt][kt][half * 4 + 0] = (short)v.x;
                B[nt][kt][half * 4 + 1] = (short)v.y;
                B[nt][kt][half * 4 + 2] = (short)v.z;
                B[nt][kt][half * 4 + 3] = (short)v.w;
            }
        }
    }
    int co = wv * 16 + lg * 4;
    #pragma unroll
    for (int nt = 0; nt < 2; ++nt) {
        f32x4 C = (f32x4){0.f, 0.f, 0.f, 0.f};
        #pragma unroll
        for (int kt = 0; kt < 4; ++kt)
            C = __builtin_amdgcn_mfma_f32_16x16x32_bf16(A[kt], B[nt][kt], C, 0, 0, 0);
        ushort4 st;
        st.x = (unsigned short)f2bf(fmaxf(C[0] + cbias[co + 0], 0.f));
        st.y = (unsigned short)f2bf(fmaxf(C[1] + cbias[co + 1], 0.f));
        st.z = (unsigned short)f2bf(fmaxf(C[2] + cbias[co + 2], 0.f));
        st.w = (unsigned short)f2bf(fmaxf(C[3] + cbias[co + 3], 0.f));
        *(ushort4*)&xch[nt * 16 + lr][co] = st;
    }
    __syncthreads();

    gru_tail<2, FIRST>(xch, hprev, w2, gbias, hnext, wv, lr, lg, y * 256 + x0);
}

// ===================== conv2 + gru2 fused =====================
template <bool FIRST>
__global__ __launch_bounds__(256, 2) void conv2_gru2(const short* __restrict__ h1Tp,
        const short* __restrict__ wA, const float* __restrict__ cbias,
        const short* __restrict__ w2, const float* __restrict__ gbias,
        const short* __restrict__ hprev, short* __restrict__ hnext) {
    __shared__ uint4 Ld[3][68][9];       // 29376 B
    __shared__ short xch[64][68];        // 8704 B
    int tid = threadIdx.x;
    int wv = tid >> 6, l = tid & 63;
    int lr = l & 15, lg = l >> 4;
    int y = blockIdx.x >> 2;
    int x0 = (blockIdx.x & 3) << 6;

    for (int n = tid; n < 3 * 68 * 8; n += 256) {
        int r = n / (68 * 8);
        int rem = n - r * (68 * 8);
        int px = rem >> 3, e = rem & 7;
        const uint4* src = (const uint4*)(h1Tp +
            (((size_t)(y + 2 * r) * P2 + (x0 + px)) << 6)) + e;
        Ld[r][px][e] = *src;
    }
    __syncthreads();

    f32x4 C[4];
    #pragma unroll
    for (int nt = 0; nt < 4; ++nt) C[nt] = (f32x4){0.f, 0.f, 0.f, 0.f};

    #pragma unroll
    for (int tap = 0; tap < 9; ++tap) {
        int r = tap / 3;
        int dx = (tap % 3 - 1) * 2;
        const short* pA = wA + (size_t)(tap * 64 + wv * 16 + lr) * 64 + lg * 8;
        bf16x8 A0 = *(const bf16x8*)(pA);
        bf16x8 A1 = *(const bf16x8*)(pA + 32);
        #pragma unroll
        for (int nt = 0; nt < 4; ++nt) {
            int xl = nt * 16 + lr + dx + 2;
            bf16x8 B0 = *(const bf16x8*)&Ld[r][xl][lg];
            bf16x8 B1 = *(const bf16x8*)&Ld[r][xl][4 + lg];
            C[nt] = __builtin_amdgcn_mfma_f32_16x16x32_bf16(A0, B0, C[nt], 0, 0, 0);
            C[nt] = __builtin_amdgcn_mfma_f32_16x16x32_bf16(A1, B1, C[nt], 0, 0, 0);
        }
    }
    int co = wv * 16 + lg * 4;
    #pragma unroll
    for (int nt = 0; nt < 4; ++nt) {
        ushort4 st;
        st.x = (unsigned short)f2bf(fmaxf(C[nt][0] + cbias[co + 0], 0.f));
        st.y = (unsigned short)f2bf(fmaxf(C[nt][1] + cbias[co + 1], 0.f));
        st.z = (unsigned short)f2bf(fmaxf(C[nt][2] + cbias[co + 2], 0.f));
        st.w = (unsigned short)f2bf(fmaxf(C[nt][3] + cbias[co + 3], 0.f));
        *(ushort4*)&xch[nt * 16 + lr][co] = st;
    }
    __syncthreads();

    gru_tail<4, FIRST>(xch, hprev, w2, gbias, hnext, wv, lr, lg, y * 256 + x0);
}

// ===================== final conv via MFMA (padded, prefetch) ==============
__global__ __launch_bounds__(256, 2) void final_mfma(const short* __restrict__ hTp,
        const short* __restrict__ wA, c32* __restrict__ eta) {
    int wv = threadIdx.x >> 6, l = threadIdx.x & 63;
    int lr = l & 15, lg = l >> 4;
    int y = blockIdx.x >> 2;
    int x0 = (blockIdx.x & 3) << 6;
    int x = x0 + wv * 16 + lr;

    auto loadB = [&](int tap, bf16x8& b0, bf16x8& b1) {
        int dy = tap / 3 - 1, dx = tap % 3 - 1;
        const short* pB = hTp +
            ((size_t)((y + dy + 2) * P2 + (x + dx + 2)) << 6) + lg * 8;
        b0 = *(const bf16x8*)(pB);
        b1 = *(const bf16x8*)(pB + 32);
    };

    f32x4 C = (f32x4){0.f, 0.f, 0.f, 0.f};
    bf16x8 cB0, cB1;
    loadB(0, cB0, cB1);
    #pragma unroll
    for (int tap = 0; tap < 9; ++tap) {
        const short* pA = wA + (size_t)(tap * 16 + lr) * 64 + lg * 8;
        bf16x8 A0 = *(const bf16x8*)(pA);
        bf16x8 A1 = *(const bf16x8*)(pA + 32);
        bf16x8 nB0, nB1;
        if (tap < 8) loadB(tap + 1, nB0, nB1);
        C = __builtin_amdgcn_mfma_f32_16x16x32_bf16(A0, cB0, C, 0, 0, 0);
        C = __builtin_amdgcn_mfma_f32_16x16x32_bf16(A1, cB1, C, 0, 0, 0);
        if (tap < 8) { cB0 = nB0; cB1 = nB1; }
    }
    if (lg == 0) {
        int px = y * 256 + x;
        c32 e = eta[px];
        eta[px] = make_float2(e.x + C[0], e.y + C[1]);
    }
}

// ===================== host orchestration =====================
extern "C" void kernel_launch(void* const* d_in, const int* in_sizes, int n_in,
                              void* d_out, int out_size, void* d_ws, size_t ws_size,
                              hipStream_t stream) {
    const c32* pred   = (const c32*)d_in[0];
    const c32* ksp    = (const c32*)d_in[1];
    const c32* sense  = (const c32*)d_in[2];
    const int* mask   = (const int*)d_in[3];
    const float* c1w  = (const float*)d_in[4];
    const float* c1b  = (const float*)d_in[5];
    const float* g1iw = (const float*)d_in[6];
    const float* g1ib = (const float*)d_in[7];
    const float* g1hw = (const float*)d_in[8];
    const float* g1hb = (const float*)d_in[9];
    const float* c2w  = (const float*)d_in[10];
    const float* c2b  = (const float*)d_in[11];
    const float* g2iw = (const float*)d_in[12];
    const float* g2ib = (const float*)d_in[13];
    const float* g2hw = (const float*)d_in[14];
    const float* g2hb = (const float*)d_in[15];
    const float* fw   = (const float*)d_in[16];
    const float* dcw  = (const float*)d_in[17];

    const size_t PP = (size_t)P2 * P2;     // 67600 padded pixels
    float* w0 = (float*)d_ws;
    c32* base = (c32*)w0;                  // NC*HW complex
    c32* Fk   = base + NC * HW;            // NC*HW complex
    c32* tmp  = Fk + NC * HW;              // NC*HW complex (init only)
    c32* eta  = tmp + NC * HW;             // HW complex
    short* gTp = (short*)(eta + HW);       // PP*4 bf16 (padded)
    short* h1Ta = gTp + PP * 4;            // PP*64 bf16 (padded)
    short* h1Tb = h1Ta + PP * 64;
    short* h2Ta = h1Tb + PP * 64;
    short* h2Tb = h2Ta + PP * 64;
    short* w2a  = h2Tb + PP * 64;          // 256*128 bf16
    short* w2b  = w2a + 256 * 128;
    float* biasA = (float*)(w2b + 256 * 128);
    float* biasB = biasA + 256;
    short* wAc2 = (short*)(biasB + 256);   // 9*64*64 bf16
    short* wAc1 = wAc2 + 9 * 64 * 64;      // 64*128 bf16
    short* wAcf = wAc1 + 64 * 128;         // 9*16*64 bf16

    dim3 B(256);
    const int gCHW = NC * HW / 256;   // 3072
    const int gHW  = HW / 256;        // 256
    const int gROW = NC * 256 / 4;    // 768
    dim3 gCOL(32, NC);                // 8-col tiles
    const int gC1 = HW / 32;          // 2048 blocks (conv1+gru1)
    const int gC2 = HW / 64;          // 1024 blocks (conv2+gru2, final)

    // border zeroing + weight prep (once per call)
    k_zero_border<<<9, B, 0, stream>>>(gTp, h1Ta, h1Tb, h2Ta, h2Tb);
    k_prep_gru<<<256, 128, 0, stream>>>(g1iw, g1ib, g1hw, g1hb, w2a, biasA);
    k_prep_gru<<<256, 128, 0, stream>>>(g2iw, g2ib, g2hw, g2hb, w2b, biasB);
    k_prep_c2<<<144, 256, 0, stream>>>(c2w, wAc2);
    k_prep_c1<<<32, 256, 0, stream>>>(c1w, wAc1);
    k_prep_cf<<<36, 256, 0, stream>>>(fw, wAcf);

    // eta0 = sum_c ifft2c(pred_c) * conj(sense_c)
    fft_rows_pre<<<gROW, B, 0, stream>>>(tmp, pred);
    fft_cols<<<gCOL, B, 0, stream>>>(tmp, -1.0f);
    k_combine_eta0<<<gHW, B, 0, stream>>>(tmp, sense, eta);

    k_base<<<gCHW, B, 0, stream>>>(ksp, pred, mask, dcw, base);

    // F_0: forward FFT of S*(eta0*sense); fused epilogue -> residual (no out)
    fft_rows_exp<<<gROW, B, 0, stream>>>(Fk, eta, sense);
    fft_cols_fused<<<gCOL, B, 0, stream>>>(Fk, base, ksp, mask, (c32*)d_out, 0);

    short* h1c = h1Ta; short* h1n = h1Tb;
    short* h2c = h2Ta; short* h2n = h2Tb;
    c32* outp = (c32*)d_out;

    for (int t = 0; t < NT; ++t) {
        fft_rows_grad<<<gHW, B, 0, stream>>>(Fk, sense, eta, gTp);

        if (t == 0) {
            conv1_gru1<true><<<gC1, B, 0, stream>>>(gTp, wAc1, c1b, w2a, biasA, h1c, h1n);
        } else {
            conv1_gru1<false><<<gC1, B, 0, stream>>>(gTp, wAc1, c1b, w2a, biasA, h1c, h1n);
        }
        { short* s = h1c; h1c = h1n; h1n = s; }
        if (t == 0) {
            conv2_gru2<true><<<gC2, B, 0, stream>>>(h1c, wAc2, c2b, w2b, biasB, h2c, h2n);
        } else {
            conv2_gru2<false><<<gC2, B, 0, stream>>>(h1c, wAc2, c2b, w2b, biasB, h2c, h2n);
        }
        { short* s = h2c; h2c = h2n; h2n = s; }
        final_mfma<<<gC2, B, 0, stream>>>(h2c, wAcf, eta);

        fft_rows_exp<<<gROW, B, 0, stream>>>(Fk, eta, sense);
        fft_cols_fused<<<gCOL, B, 0, stream>>>(Fk, base, ksp, mask,
                                               outp + (size_t)t * NC * HW, 1);
    }
}

// Round 17
// 884.731 us; speedup vs baseline: 1.0238x; 1.0238x over previous
//
#include <hip/hip_runtime.h>

#define HW 65536
#define NC 12
#define NF 64
#define NT 8
#define P2 260   // padded pitch (2-wide zero border each side)

typedef float2 c32;
typedef __attribute__((ext_vector_type(8))) short bf16x8;   // 8 bf16 = 4 VGPR
typedef __attribute__((ext_vector_type(4))) float f32x4;    // MFMA C/D

__device__ __forceinline__ float ssign(int p) {
    return ((p ^ (p >> 8)) & 1) ? -1.0f : 1.0f;
}

__device__ __forceinline__ short f2bf(float f) {   // RNE float->bf16
    union { float f; unsigned u; } v; v.f = f;
    unsigned r = (v.u + 0x7FFFu + ((v.u >> 16) & 1u)) >> 16;
    return (short)r;
}

__device__ __forceinline__ float bf2f(unsigned short u) {
    union { unsigned u; float f; } v; v.u = (unsigned)u << 16;
    return v.f;
}

// ===================== 256-point FFT =====================
// Variant A: one wave per line (64 lanes, 2 butterflies/stage via stage-pairs).
__device__ __forceinline__ void wave_sync() {
    asm volatile("s_waitcnt lgkmcnt(0)" ::: "memory");
}

__device__ __forceinline__ void fft256_wave(c32* X, const c32* tw, int j, float conjf) {
    #pragma unroll
    for (int s = 1; s <= 8; s += 2) {
        const int H = 1 << (s - 1);
        int p = j & (H - 1);
        int r = j >> (s - 1);
        int i0 = r * 4 * H + p;
        c32 e0 = X[i0], e1 = X[i0 + H], e2 = X[i0 + 2 * H], e3 = X[i0 + 3 * H];
        c32 w = tw[p << (8 - s)];
        float wy = conjf * w.y;
        c32 t = make_float2(w.x * e1.x - wy * e1.y, w.x * e1.y + wy * e1.x);
        c32 a0 = make_float2(e0.x + t.x, e0.y + t.y);
        c32 a1 = make_float2(e0.x - t.x, e0.y - t.y);
        t = make_float2(w.x * e3.x - wy * e3.y, w.x * e3.y + wy * e3.x);
        c32 a2 = make_float2(e2.x + t.x, e2.y + t.y);
        c32 a3 = make_float2(e2.x - t.x, e2.y - t.y);
        c32 w0 = tw[p << (7 - s)];
        c32 w1 = tw[(p + H) << (7 - s)];
        float w0y = conjf * w0.y, w1y = conjf * w1.y;
        t = make_float2(w0.x * a2.x - w0y * a2.y, w0.x * a2.y + w0y * a2.x);
        X[i0]         = make_float2(a0.x + t.x, a0.y + t.y);
        X[i0 + 2 * H] = make_float2(a0.x - t.x, a0.y - t.y);
        t = make_float2(w1.x * a3.x - w1y * a3.y, w1.x * a3.y + w1y * a3.x);
        X[i0 + H]     = make_float2(a1.x + t.x, a1.y + t.y);
        X[i0 + 3 * H] = make_float2(a1.x - t.x, a1.y - t.y);
        wave_sync();
    }
}

// Variant B: two waves per line (128 lanes, 1 butterfly/lane/stage).
// Block-wide __syncthreads per stage; bit-identical butterflies.
__device__ __forceinline__ void fft256_2w(c32* X, const c32* tw, int lane, float conjf) {
    #pragma unroll
    for (int s = 1; s <= 8; ++s) {
        const int half = 1 << (s - 1);
        int grp = lane >> (s - 1);
        int pos = lane & (half - 1);
        int i0 = (grp << s) + pos;
        int i1 = i0 + half;
        c32 w = tw[pos << (8 - s)];
        float wy = conjf * w.y;
        c32 a = X[i0], cc = X[i1];
        c32 t = make_float2(w.x * cc.x - wy * cc.y, w.x * cc.y + wy * cc.x);
        X[i0] = make_float2(a.x + t.x, a.y + t.y);
        X[i1] = make_float2(a.x - t.x, a.y - t.y);
        __syncthreads();
    }
}

__device__ __forceinline__ void build_tw(c32* tw, int tid) {
    if (tid < 128) {
        float a = -3.14159265358979323846f * (float)tid * (1.0f / 128.0f);
        float sv, cv;
        sincosf(a, &sv, &cv);
        tw[tid] = make_float2(cv, sv);
    }
}

// Row inverse FFT, fused load X = S*pred. grid 1536, 256 thr (2 lines x 2 waves).
__global__ __launch_bounds__(256) void fft_rows_pre(c32* __restrict__ buf,
        const c32* __restrict__ pred) {
    __shared__ c32 lds[2][256];
    __shared__ c32 tw[128];
    int tid = threadIdx.x;
    build_tw(tw, tid);
    int li = tid >> 7, lane = tid & 127;
    int r = blockIdx.x * 2 + li;
    int coil = r >> 8, y = r & 255;
    c32* rp = buf + (size_t)r * 256;
    c32* X = lds[li];
    #pragma unroll
    for (int e = 0; e < 2; ++e) {
        int n = (e << 7) + lane;
        float s = ((n + y) & 1) ? -1.0f : 1.0f;
        c32 pv = pred[(size_t)coil * HW + y * 256 + n];
        X[__brev((unsigned)n) >> 24] = make_float2(s * pv.x, s * pv.y);
    }
    __syncthreads();
    fft256_2w(X, tw, lane, -1.0f);   // ends with __syncthreads
    #pragma unroll
    for (int e = 0; e < 2; ++e) {
        int n = (e << 7) + lane;
        rp[n] = X[n];
    }
}

// Row forward FFT, fused load X = S*eta*sense. grid 1536, 256 thr.
__global__ __launch_bounds__(256) void fft_rows_exp(c32* __restrict__ buf,
        const c32* __restrict__ eta, const c32* __restrict__ sense) {
    __shared__ c32 lds[2][256];
    __shared__ c32 tw[128];
    int tid = threadIdx.x;
    build_tw(tw, tid);
    int li = tid >> 7, lane = tid & 127;
    int r = blockIdx.x * 2 + li;
    int coil = r >> 8, y = r & 255;
    c32* rp = buf + (size_t)r * 256;
    c32* X = lds[li];
    #pragma unroll
    for (int e = 0; e < 2; ++e) {
        int n = (e << 7) + lane;
        float s = ((n + y) & 1) ? -1.0f : 1.0f;
        c32 ev = eta[y * 256 + n];
        c32 sn = sense[(size_t)coil * HW + y * 256 + n];
        X[__brev((unsigned)n) >> 24] =
            make_float2(s * (ev.x * sn.x - ev.y * sn.y),
                        s * (ev.x * sn.y + ev.y * sn.x));
    }
    __syncthreads();
    fft256_2w(X, tw, lane, 1.0f);
    #pragma unroll
    for (int e = 0; e < 2; ++e) {
        int n = (e << 7) + lane;
        rp[n] = X[n];
    }
}

// Merged: row-inverse FFT of all 12 coils of row y + coil-combine + g emit.
// grid 256, 768 thr (12 waves, 1 wave per coil line).
__global__ __launch_bounds__(768) void fft_rows_grad(const c32* __restrict__ Fk,
        const c32* __restrict__ sense, const c32* __restrict__ eta,
        short* __restrict__ gTp) {
    __shared__ c32 lds[12][256];     // 24 KB
    __shared__ c32 tw[128];
    int tid = threadIdx.x;
    build_tw(tw, tid);
    int wid = tid >> 6, j = tid & 63;   // wid 0..11
    int y = blockIdx.x;
    {
        const c32* rp = Fk + (size_t)wid * HW + y * 256;
        #pragma unroll
        for (int e = 0; e < 4; ++e) {
            int n = (e << 6) + j;
            lds[wid][__brev((unsigned)n) >> 24] = rp[n];
        }
    }
    __syncthreads();
    fft256_wave(&lds[wid][0], tw, j, -1.0f);
    __syncthreads();
    if (tid < 256) {
        int x = tid;
        int p = y * 256 + x;
        float ax = 0.f, ay = 0.f;
        #pragma unroll
        for (int c = 0; c < NC; ++c) {
            c32 t = lds[c][x];
            c32 s = sense[(size_t)c * HW + p];
            ax += t.x * s.x + t.y * s.y;
            ay += t.y * s.x - t.x * s.y;
        }
        float sc = (((x + y) & 1) ? -1.0f : 1.0f) * (1.0f / 256.0f);
        c32 e = eta[p];
        ushort4 o;
        o.x = (unsigned short)f2bf(e.x);
        o.y = (unsigned short)f2bf(e.y);
        o.z = (unsigned short)f2bf(ax * sc);
        o.w = (unsigned short)f2bf(ay * sc);
        ((ushort4*)gTp)[(y + 2) * P2 + x + 2] = o;
    }
}

// 8-column col FFT (init inverse only). grid (32, NC), 1024 thr (8 cols x 2 waves).
__global__ __launch_bounds__(1024) void fft_cols(c32* __restrict__ buf, float conjf) {
    __shared__ c32 lds[8][257];
    __shared__ c32 tw[128];
    int tid = threadIdx.x;
    build_tw(tw, tid);
    c32* ip = buf + (size_t)blockIdx.y * HW;
    int x0 = blockIdx.x * 8;
    int xl = tid & 7, yb = tid >> 3;     // yb 0..127
    #pragma unroll
    for (int e = 0; e < 2; ++e) {
        int y = yb + (e << 7);
        lds[xl][__brev((unsigned)y) >> 24] = ip[y * 256 + x0 + xl];
    }
    __syncthreads();
    int col = tid >> 7, lane = tid & 127;
    fft256_2w(&lds[col][0], tw, lane, conjf);
    #pragma unroll
    for (int e = 0; e < 2; ++e) {
        int y = yb + (e << 7);
        ip[y * 256 + x0 + xl] = lds[xl][y];
    }
}

// 8-column fused: fwd col FFT -> (out + masked residual) -> inv col FFT.
// grid (32, NC), 1024 thr.
__global__ __launch_bounds__(1024) void fft_cols_fused(c32* __restrict__ buf,
        const c32* __restrict__ base, const c32* __restrict__ ksp,
        const int* __restrict__ mask, c32* __restrict__ outp, int write_out) {
    __shared__ c32 lds[8][257];
    __shared__ c32 tw[128];
    int tid = threadIdx.x;
    build_tw(tw, tid);
    int coil = blockIdx.y;
    c32* ip = buf + (size_t)coil * HW;
    int x0 = blockIdx.x * 8;
    int xl = tid & 7, yb = tid >> 3;
    #pragma unroll
    for (int e = 0; e < 2; ++e) {
        int y = yb + (e << 7);
        lds[xl][__brev((unsigned)y) >> 24] = ip[y * 256 + x0 + xl];
    }
    __syncthreads();
    int col = tid >> 7, lane = tid & 127;
    fft256_2w(&lds[col][0], tw, lane, 1.0f);   // ends with barrier

    int x = x0 + xl;
    c32 G[2];
    #pragma unroll
    for (int e = 0; e < 2; ++e) {
        int y = yb + (e << 7);
        G[e] = lds[xl][y];
    }
    __syncthreads();
    #pragma unroll
    for (int e = 0; e < 2; ++e) {
        int y = yb + (e << 7);
        int p = y * 256 + x;
        size_t i = (size_t)coil * HW + p;
        float s = ((p ^ (p >> 8)) & 1) ? -1.0f : 1.0f;
        if (write_out) {
            c32 bv = base[i];
            float sc = s * (1.0f / 256.0f);
            outp[i] = make_float2(bv.x - sc * G[e].x, bv.y - sc * G[e].y);
        }
        c32 rv = make_float2(0.f, 0.f);
        if (mask[p]) {
            c32 k = ksp[i];
            rv = make_float2(G[e].x * (1.0f / 256.0f) - s * k.x,
                             G[e].y * (1.0f / 256.0f) - s * k.y);
        }
        lds[xl][__brev((unsigned)y) >> 24] = rv;
    }
    __syncthreads();
    fft256_2w(&lds[col][0], tw, lane, -1.0f);
    #pragma unroll
    for (int e = 0; e < 2; ++e) {
        int y = yb + (e << 7);
        ip[y * 256 + x0 + xl] = lds[xl][y];
    }
}

// ===================== pointwise kernels =====================
__global__ __launch_bounds__(256) void k_combine_eta0(const c32* __restrict__ tmp,
        const c32* __restrict__ sense, c32* __restrict__ eta) {
    int p = blockIdx.x * 256 + threadIdx.x;
    float ax = 0.f, ay = 0.f;
    for (int c = 0; c < NC; ++c) {
        c32 t = tmp[c * HW + p], s = sense[c * HW + p];
        ax += t.x * s.x + t.y * s.y;
        ay += t.y * s.x - t.x * s.y;
    }
    float sc = ssign(p) * (1.0f / 256.0f);
    eta[p] = make_float2(ax * sc, ay * sc);
}

__global__ __launch_bounds__(256) void k_base(const c32* __restrict__ ksp,
        const c32* __restrict__ pred, const int* __restrict__ mask,
        const float* __restrict__ dcw, c32* __restrict__ base) {
    int i = blockIdx.x * 256 + threadIdx.x;
    int p = i & (HW - 1);
    c32 k = ksp[i];
    c32 o = k;
    if (mask[p]) {
        float w = dcw[0];
        c32 pr = pred[i];
        o.x -= (pr.x - k.x) * w;
        o.y -= (pr.y - k.y) * w;
    }
    base[i] = o;
}

// Zero the border pixels of gTp + the 4 padded h buffers.
__global__ __launch_bounds__(256) void k_zero_border(short* __restrict__ gTp,
        short* __restrict__ h1a, short* __restrict__ h1b,
        short* __restrict__ h2a, short* __restrict__ h2b) {
    int i = blockIdx.x * 256 + threadIdx.x;
    if (i >= 2064) return;
    int y, x;
    if (i < 1040) {
        int r = i / 260;
        y = (r < 2) ? r : 256 + r;
        x = i % 260;
    } else {
        int j = i - 1040;
        y = 2 + (j >> 2);
        int cix = j & 3;
        x = (cix < 2) ? cix : 256 + cix;
    }
    size_t px = (size_t)y * P2 + x;
    ((ushort4*)gTp)[px] = make_ushort4(0, 0, 0, 0);
    uint4 z = make_uint4(0, 0, 0, 0);
    uint4* p1 = (uint4*)(h1a + (px << 6));
    uint4* p2 = (uint4*)(h1b + (px << 6));
    uint4* p3 = (uint4*)(h2a + (px << 6));
    uint4* p4 = (uint4*)(h2b + (px << 6));
    #pragma unroll
    for (int e = 0; e < 8; ++e) { p1[e] = z; p2[e] = z; p3[e] = z; p4[e] = z; }
}

// ===================== weight prep kernels =====================
__global__ __launch_bounds__(256) void k_prep_c1(const float* __restrict__ w,
        short* __restrict__ wA) {
    int i = blockIdx.x * 256 + threadIdx.x;    // 64*128
    int co = i >> 7, k = i & 127;
    int tap = k >> 2, ci = k & 3;
    float v = (tap < 25) ? w[co * 100 + ci * 25 + tap] : 0.f;
    wA[i] = f2bf(v);
}

__global__ __launch_bounds__(256) void k_prep_c2(const float* __restrict__ w,
        short* __restrict__ wA) {
    int i = blockIdx.x * 256 + threadIdx.x;     // 36864
    int tap = i >> 12, co = (i >> 6) & 63, ci = i & 63;
    wA[i] = f2bf(w[co * 576 + ci * 9 + tap]);
}

__global__ __launch_bounds__(256) void k_prep_cf(const float* __restrict__ w,
        short* __restrict__ wA) {
    int i = blockIdx.x * 256 + threadIdx.x;    // 9216
    int tap = i >> 10, r = (i >> 6) & 15, ci = i & 63;
    float v = (r < 2) ? w[r * 576 + ci * 9 + tap] : 0.f;
    wA[i] = f2bf(v);
}

__global__ __launch_bounds__(128) void k_prep_gru(const float* __restrict__ ihw,
        const float* __restrict__ ihb, const float* __restrict__ hhw,
        const float* __restrict__ hhb, short* __restrict__ w2, float* __restrict__ bias) {
    int k = threadIdx.x;
    int r = blockIdx.x;
    int g = r >> 6, co = r & 63;
    float v = 0.f;
    if (g == 0)      v = (k < 64) ? ihw[co * 64 + k]         : hhw[co * 64 + k - 64];
    else if (g == 1) v = (k < 64) ? ihw[(64 + co) * 64 + k]  : hhw[(64 + co) * 64 + k - 64];
    else if (g == 2) v = (k < 64) ? ihw[(128 + co) * 64 + k] : 0.f;
    else             v = (k < 64) ? 0.f : hhw[(128 + co) * 64 + k - 64];
    w2[r * 128 + k] = f2bf(v);
    if (k == 0) {
        float b = (g == 0) ? ihb[co] + hhb[co]
                : (g == 1) ? ihb[64 + co] + hhb[64 + co]
                : (g == 2) ? ihb[128 + co] : hhb[128 + co];
        bias[r] = b;
    }
}

// ===================== shared GRU tail (x from LDS, h from global) =========
template <int NTN, bool FIRST>
__device__ __forceinline__ void gru_tail(const short (*xch)[68],
        const short* __restrict__ hprev, const short* __restrict__ w2,
        const float* __restrict__ bias, short* __restrict__ hnext,
        int wv, int lr, int lg, int px0) {
    bf16x8 A0[4], A1[4], A2[2], A3[2];
    {
        const short* w0 = w2 + (0   + wv * 16 + lr) * 128 + lg * 8;
        const short* w1 = w2 + (64  + wv * 16 + lr) * 128 + lg * 8;
        const short* w2p = w2 + (128 + wv * 16 + lr) * 128 + lg * 8;
        const short* w3 = w2 + (192 + wv * 16 + lr) * 128 + lg * 8;
        #pragma unroll
        for (int kt = 0; kt < 4; ++kt) {
            A0[kt] = *(const bf16x8*)(w0 + kt * 32);
            A1[kt] = *(const bf16x8*)(w1 + kt * 32);
        }
        A2[0] = *(const bf16x8*)(w2p);          A2[1] = *(const bf16x8*)(w2p + 32);
        A3[0] = *(const bf16x8*)(w3 + 64);      A3[1] = *(const bf16x8*)(w3 + 96);
    }

    f32x4 C0[NTN], C1[NTN], C2[NTN], C3[NTN];
    #pragma unroll
    for (int nt = 0; nt < NTN; ++nt) {
        C0[nt] = (f32x4){0.f, 0.f, 0.f, 0.f};
        C1[nt] = (f32x4){0.f, 0.f, 0.f, 0.f};
        C2[nt] = (f32x4){0.f, 0.f, 0.f, 0.f};
        C3[nt] = (f32x4){0.f, 0.f, 0.f, 0.f};
    }

    #pragma unroll
    for (int nt = 0; nt < NTN; ++nt) {
        int pxl = nt * 16 + lr;
        int px = px0 + pxl;
        int yy = px >> 8, xx = px & 255;
        size_t pb = ((size_t)((yy + 2) * P2 + (xx + 2)) << 6);
        bf16x8 B0 = *(const bf16x8*)&xch[pxl][lg * 8];
        bf16x8 B1 = *(const bf16x8*)&xch[pxl][32 + lg * 8];
        C0[nt] = __builtin_amdgcn_mfma_f32_16x16x32_bf16(A0[0], B0, C0[nt], 0, 0, 0);
        C0[nt] = __builtin_amdgcn_mfma_f32_16x16x32_bf16(A0[1], B1, C0[nt], 0, 0, 0);
        C1[nt] = __builtin_amdgcn_mfma_f32_16x16x32_bf16(A1[0], B0, C1[nt], 0, 0, 0);
        C1[nt] = __builtin_amdgcn_mfma_f32_16x16x32_bf16(A1[1], B1, C1[nt], 0, 0, 0);
        C2[nt] = __builtin_amdgcn_mfma_f32_16x16x32_bf16(A2[0], B0, C2[nt], 0, 0, 0);
        C2[nt] = __builtin_amdgcn_mfma_f32_16x16x32_bf16(A2[1], B1, C2[nt], 0, 0, 0);
        if (!FIRST) {
            bf16x8 B2 = *(const bf16x8*)(hprev + pb + lg * 8);
            bf16x8 B3 = *(const bf16x8*)(hprev + pb + 32 + lg * 8);
            C0[nt] = __builtin_amdgcn_mfma_f32_16x16x32_bf16(A0[2], B2, C0[nt], 0, 0, 0);
            C0[nt] = __builtin_amdgcn_mfma_f32_16x16x32_bf16(A0[3], B3, C0[nt], 0, 0, 0);
            C1[nt] = __builtin_amdgcn_mfma_f32_16x16x32_bf16(A1[2], B2, C1[nt], 0, 0, 0);
            C1[nt] = __builtin_amdgcn_mfma_f32_16x16x32_bf16(A1[3], B3, C1[nt], 0, 0, 0);
            C3[nt] = __builtin_amdgcn_mfma_f32_16x16x32_bf16(A3[0], B2, C3[nt], 0, 0, 0);
            C3[nt] = __builtin_amdgcn_mfma_f32_16x16x32_bf16(A3[1], B3, C3[nt], 0, 0, 0);
        }
    }

    int co = wv * 16 + lg * 4;
    float br[4], bz[4], bin_[4], bhn[4];
    #pragma unroll
    for (int i = 0; i < 4; ++i) {
        br[i]   = bias[co + i];
        bz[i]   = bias[64 + co + i];
        bin_[i] = bias[128 + co + i];
        bhn[i]  = bias[192 + co + i];
    }
    #pragma unroll
    for (int nt = 0; nt < NTN; ++nt) {
        int px = px0 + nt * 16 + lr;
        int yy = px >> 8, xx = px & 255;
        size_t pb = ((size_t)((yy + 2) * P2 + (xx + 2)) << 6);
        ushort4 hov = make_ushort4(0, 0, 0, 0);
        if (!FIRST) hov = *(const ushort4*)(hprev + pb + co);
        float ho[4] = {bf2f(hov.x), bf2f(hov.y), bf2f(hov.z), bf2f(hov.w)};
        ushort4 st;
        unsigned short* sp = &st.x;
        #pragma unroll
        for (int i = 0; i < 4; ++i) {
            float r = 1.0f / (1.0f + expf(-(C0[nt][i] + br[i])));
            float z = 1.0f / (1.0f + expf(-(C1[nt][i] + bz[i])));
            float nn = tanhf(C2[nt][i] + bin_[i] + r * (C3[nt][i] + bhn[i]));
            float hv = FIRST ? (1.0f - z) * nn : (1.0f - z) * nn + z * ho[i];
            sp[i] = (unsigned short)f2bf(hv);
        }
        *(ushort4*)(hnext + pb + co) = st;
    }
}

// ===================== conv1 + gru1 fused =====================
template <bool FIRST>
__global__ __launch_bounds__(256, 2) void conv1_gru1(const short* __restrict__ gTp,
        const short* __restrict__ wA, const float* __restrict__ cbias,
        const short* __restrict__ w2, const float* __restrict__ gbias,
        const short* __restrict__ hprev, short* __restrict__ hnext) {
    __shared__ short xch[32][68];
    int wv = threadIdx.x >> 6, l = threadIdx.x & 63;
    int lr = l & 15, lg = l >> 4;
    int y = blockIdx.x >> 3;
    int x0 = (blockIdx.x & 7) << 5;

    bf16x8 A[4];
    const short* pA = wA + (size_t)(wv * 16 + lr) * 128 + lg * 8;
    #pragma unroll
    for (int kt = 0; kt < 4; ++kt) A[kt] = *(const bf16x8*)(pA + kt * 32);

    bf16x8 B[2][4];
    #pragma unroll
    for (int nt = 0; nt < 2; ++nt) {
        int x = x0 + nt * 16 + lr;
        #pragma unroll
        for (int kt = 0; kt < 4; ++kt) {
            int t0 = kt * 8 + lg * 2;
            #pragma unroll
            for (int half = 0; half < 2; ++half) {
                int tap = t0 + half;
                int tt = (tap < 25) ? tap : 0;
                int dy = tt / 5 - 2, dx = tt % 5 - 2;
                ushort4 v = *(const ushort4*)(gTp +
                    ((size_t)((y + dy + 2) * P2 + (x + dx + 2)) << 2));
                B[nt][kt][half * 4 + 0] = (short)v.x;
                B[nt][kt][half * 4 + 1] = (short)v.y;
                B[nt][kt][half * 4 + 2] = (short)v.z;
                B[nt][kt][half * 4 + 3] = (short)v.w;
            }
        }
    }
    int co = wv * 16 + lg * 4;
    #pragma unroll
    for (int nt = 0; nt < 2; ++nt) {
        f32x4 C = (f32x4){0.f, 0.f, 0.f, 0.f};
        #pragma unroll
        for (int kt = 0; kt < 4; ++kt)
            C = __builtin_amdgcn_mfma_f32_16x16x32_bf16(A[kt], B[nt][kt], C, 0, 0, 0);
        ushort4 st;
        st.x = (unsigned short)f2bf(fmaxf(C[0] + cbias[co + 0], 0.f));
        st.y = (unsigned short)f2bf(fmaxf(C[1] + cbias[co + 1], 0.f));
        st.z = (unsigned short)f2bf(fmaxf(C[2] + cbias[co + 2], 0.f));
        st.w = (unsigned short)f2bf(fmaxf(C[3] + cbias[co + 3], 0.f));
        *(ushort4*)&xch[nt * 16 + lr][co] = st;
    }
    __syncthreads();

    gru_tail<2, FIRST>(xch, hprev, w2, gbias, hnext, wv, lr, lg, y * 256 + x0);
}

// ===================== conv2 + gru2 fused =====================
template <bool FIRST>
__global__ __launch_bounds__(256, 2) void conv2_gru2(const short* __restrict__ h1Tp,
        const short* __restrict__ wA, const float* __restrict__ cbias,
        const short* __restrict__ w2, const float* __restrict__ gbias,
        const short* __restrict__ hprev, short* __restrict__ hnext) {
    __shared__ uint4 Ld[3][68][9];       // 29376 B
    __shared__ short xch[64][68];        // 8704 B
    int tid = threadIdx.x;
    int wv = tid >> 6, l = tid & 63;
    int lr = l & 15, lg = l >> 4;
    int y = blockIdx.x >> 2;
    int x0 = (blockIdx.x & 3) << 6;

    for (int n = tid; n < 3 * 68 * 8; n += 256) {
        int r = n / (68 * 8);
        int rem = n - r * (68 * 8);
        int px = rem >> 3, e = rem & 7;
        const uint4* src = (const uint4*)(h1Tp +
            (((size_t)(y + 2 * r) * P2 + (x0 + px)) << 6)) + e;
        Ld[r][px][e] = *src;
    }
    __syncthreads();

    f32x4 C[4];
    #pragma unroll
    for (int nt = 0; nt < 4; ++nt) C[nt] = (f32x4){0.f, 0.f, 0.f, 0.f};

    #pragma unroll
    for (int tap = 0; tap < 9; ++tap) {
        int r = tap / 3;
        int dx = (tap % 3 - 1) * 2;
        const short* pA = wA + (size_t)(tap * 64 + wv * 16 + lr) * 64 + lg * 8;
        bf16x8 A0 = *(const bf16x8*)(pA);
        bf16x8 A1 = *(const bf16x8*)(pA + 32);
        #pragma unroll
        for (int nt = 0; nt < 4; ++nt) {
            int xl = nt * 16 + lr + dx + 2;
            bf16x8 B0 = *(const bf16x8*)&Ld[r][xl][lg];
            bf16x8 B1 = *(const bf16x8*)&Ld[r][xl][4 + lg];
            C[nt] = __builtin_amdgcn_mfma_f32_16x16x32_bf16(A0, B0, C[nt], 0, 0, 0);
            C[nt] = __builtin_amdgcn_mfma_f32_16x16x32_bf16(A1, B1, C[nt], 0, 0, 0);
        }
    }
    int co = wv * 16 + lg * 4;
    #pragma unroll
    for (int nt = 0; nt < 4; ++nt) {
        ushort4 st;
        st.x = (unsigned short)f2bf(fmaxf(C[nt][0] + cbias[co + 0], 0.f));
        st.y = (unsigned short)f2bf(fmaxf(C[nt][1] + cbias[co + 1], 0.f));
        st.z = (unsigned short)f2bf(fmaxf(C[nt][2] + cbias[co + 2], 0.f));
        st.w = (unsigned short)f2bf(fmaxf(C[nt][3] + cbias[co + 3], 0.f));
        *(ushort4*)&xch[nt * 16 + lr][co] = st;
    }
    __syncthreads();

    gru_tail<4, FIRST>(xch, hprev, w2, gbias, hnext, wv, lr, lg, y * 256 + x0);
}

// ===================== final conv via MFMA (padded, prefetch) ==============
__global__ __launch_bounds__(256, 2) void final_mfma(const short* __restrict__ hTp,
        const short* __restrict__ wA, c32* __restrict__ eta) {
    int wv = threadIdx.x >> 6, l = threadIdx.x & 63;
    int lr = l & 15, lg = l >> 4;
    int y = blockIdx.x >> 2;
    int x0 = (blockIdx.x & 3) << 6;
    int x = x0 + wv * 16 + lr;

    auto loadB = [&](int tap, bf16x8& b0, bf16x8& b1) {
        int dy = tap / 3 - 1, dx = tap % 3 - 1;
        const short* pB = hTp +
            ((size_t)((y + dy + 2) * P2 + (x + dx + 2)) << 6) + lg * 8;
        b0 = *(const bf16x8*)(pB);
        b1 = *(const bf16x8*)(pB + 32);
    };

    f32x4 C = (f32x4){0.f, 0.f, 0.f, 0.f};
    bf16x8 cB0, cB1;
    loadB(0, cB0, cB1);
    #pragma unroll
    for (int tap = 0; tap < 9; ++tap) {
        const short* pA = wA + (size_t)(tap * 16 + lr) * 64 + lg * 8;
        bf16x8 A0 = *(const bf16x8*)(pA);
        bf16x8 A1 = *(const bf16x8*)(pA + 32);
        bf16x8 nB0, nB1;
        if (tap < 8) loadB(tap + 1, nB0, nB1);
        C = __builtin_amdgcn_mfma_f32_16x16x32_bf16(A0, cB0, C, 0, 0, 0);
        C = __builtin_amdgcn_mfma_f32_16x16x32_bf16(A1, cB1, C, 0, 0, 0);
        if (tap < 8) { cB0 = nB0; cB1 = nB1; }
    }
    if (lg == 0) {
        int px = y * 256 + x;
        c32 e = eta[px];
        eta[px] = make_float2(e.x + C[0], e.y + C[1]);
    }
}

// ===================== host orchestration =====================
extern "C" void kernel_launch(void* const* d_in, const int* in_sizes, int n_in,
                              void* d_out, int out_size, void* d_ws, size_t ws_size,
                              hipStream_t stream) {
    const c32* pred   = (const c32*)d_in[0];
    const c32* ksp    = (const c32*)d_in[1];
    const c32* sense  = (const c32*)d_in[2];
    const int* mask   = (const int*)d_in[3];
    const float* c1w  = (const float*)d_in[4];
    const float* c1b  = (const float*)d_in[5];
    const float* g1iw = (const float*)d_in[6];
    const float* g1ib = (const float*)d_in[7];
    const float* g1hw = (const float*)d_in[8];
    const float* g1hb = (const float*)d_in[9];
    const float* c2w  = (const float*)d_in[10];
    const float* c2b  = (const float*)d_in[11];
    const float* g2iw = (const float*)d_in[12];
    const float* g2ib = (const float*)d_in[13];
    const float* g2hw = (const float*)d_in[14];
    const float* g2hb = (const float*)d_in[15];
    const float* fw   = (const float*)d_in[16];
    const float* dcw  = (const float*)d_in[17];

    const size_t PP = (size_t)P2 * P2;     // 67600 padded pixels
    float* w0 = (float*)d_ws;
    c32* base = (c32*)w0;                  // NC*HW complex
    c32* Fk   = base + NC * HW;            // NC*HW complex
    c32* tmp  = Fk + NC * HW;              // NC*HW complex (init only)
    c32* eta  = tmp + NC * HW;             // HW complex
    short* gTp = (short*)(eta + HW);       // PP*4 bf16 (padded)
    short* h1Ta = gTp + PP * 4;            // PP*64 bf16 (padded)
    short* h1Tb = h1Ta + PP * 64;
    short* h2Ta = h1Tb + PP * 64;
    short* h2Tb = h2Ta + PP * 64;
    short* w2a  = h2Tb + PP * 64;          // 256*128 bf16
    short* w2b  = w2a + 256 * 128;
    float* biasA = (float*)(w2b + 256 * 128);
    float* biasB = biasA + 256;
    short* wAc2 = (short*)(biasB + 256);   // 9*64*64 bf16
    short* wAc1 = wAc2 + 9 * 64 * 64;      // 64*128 bf16
    short* wAcf = wAc1 + 64 * 128;         // 9*16*64 bf16

    dim3 B(256);
    const int gCHW = NC * HW / 256;   // 3072
    const int gHW  = HW / 256;        // 256
    const int gROW = NC * 256 / 2;    // 1536 (2 rows/block)
    dim3 gCOL(32, NC);                // 8-col tiles, 1024 thr
    dim3 B1024(1024);
    dim3 B768(768);
    const int gC1 = HW / 32;          // 2048 blocks (conv1+gru1)
    const int gC2 = HW / 64;          // 1024 blocks (conv2+gru2, final)

    // border zeroing + weight prep (once per call)
    k_zero_border<<<9, B, 0, stream>>>(gTp, h1Ta, h1Tb, h2Ta, h2Tb);
    k_prep_gru<<<256, 128, 0, stream>>>(g1iw, g1ib, g1hw, g1hb, w2a, biasA);
    k_prep_gru<<<256, 128, 0, stream>>>(g2iw, g2ib, g2hw, g2hb, w2b, biasB);
    k_prep_c2<<<144, 256, 0, stream>>>(c2w, wAc2);
    k_prep_c1<<<32, 256, 0, stream>>>(c1w, wAc1);
    k_prep_cf<<<36, 256, 0, stream>>>(fw, wAcf);

    // eta0 = sum_c ifft2c(pred_c) * conj(sense_c)
    fft_rows_pre<<<gROW, B, 0, stream>>>(tmp, pred);
    fft_cols<<<gCOL, B1024, 0, stream>>>(tmp, -1.0f);
    k_combine_eta0<<<gHW, B, 0, stream>>>(tmp, sense, eta);

    k_base<<<gCHW, B, 0, stream>>>(ksp, pred, mask, dcw, base);

    // F_0: forward FFT of S*(eta0*sense); fused epilogue -> residual (no out)
    fft_rows_exp<<<gROW, B, 0, stream>>>(Fk, eta, sense);
    fft_cols_fused<<<gCOL, B1024, 0, stream>>>(Fk, base, ksp, mask, (c32*)d_out, 0);

    short* h1c = h1Ta; short* h1n = h1Tb;
    short* h2c = h2Ta; short* h2n = h2Tb;
    c32* outp = (c32*)d_out;

    for (int t = 0; t < NT; ++t) {
        fft_rows_grad<<<gHW, B768, 0, stream>>>(Fk, sense, eta, gTp);

        if (t == 0) {
            conv1_gru1<true><<<gC1, B, 0, stream>>>(gTp, wAc1, c1b, w2a, biasA, h1c, h1n);
        } else {
            conv1_gru1<false><<<gC1, B, 0, stream>>>(gTp, wAc1, c1b, w2a, biasA, h1c, h1n);
        }
        { short* s = h1c; h1c = h1n; h1n = s; }
        if (t == 0) {
            conv2_gru2<true><<<gC2, B, 0, stream>>>(h1c, wAc2, c2b, w2b, biasB, h2c, h2n);
        } else {
            conv2_gru2<false><<<gC2, B, 0, stream>>>(h1c, wAc2, c2b, w2b, biasB, h2c, h2n);
        }
        { short* s = h2c; h2c = h2n; h2n = s; }
        final_mfma<<<gC2, B, 0, stream>>>(h2c, wAcf, eta);

        fft_rows_exp<<<gROW, B, 0, stream>>>(Fk, eta, sense);
        fft_cols_fused<<<gCOL, B1024, 0, stream>>>(Fk, base, ksp, mask,
                                                   outp + (size_t)t * NC * HW, 1);
    }
}

// Round 18
// 852.969 us; speedup vs baseline: 1.0619x; 1.0372x over previous
//
#include <hip/hip_runtime.h>

#define HW 65536
#define NC 12
#define NF 64
#define NT 8
#define P2 260   // padded pitch (2-wide zero border each side)

typedef float2 c32;
typedef __attribute__((ext_vector_type(8))) short bf16x8;   // 8 bf16 = 4 VGPR
typedef __attribute__((ext_vector_type(4))) float f32x4;    // MFMA C/D

__device__ __forceinline__ float ssign(int p) {
    return ((p ^ (p >> 8)) & 1) ? -1.0f : 1.0f;
}

__device__ __forceinline__ short f2bf(float f) {   // RNE float->bf16
    union { float f; unsigned u; } v; v.f = f;
    unsigned r = (v.u + 0x7FFFu + ((v.u >> 16) & 1u)) >> 16;
    return (short)r;
}

__device__ __forceinline__ float bf2f(unsigned short u) {
    union { unsigned u; float f; } v; v.u = (unsigned)u << 16;
    return v.f;
}

// ===================== 256-point FFT =====================
__device__ __forceinline__ void wave_sync() {
    asm volatile("s_waitcnt lgkmcnt(0)" ::: "memory");
}

// Variant A: one wave per line (stage-pairs, 4 syncs).
__device__ __forceinline__ void fft256_wave(c32* X, const c32* tw, int j, float conjf) {
    #pragma unroll
    for (int s = 1; s <= 8; s += 2) {
        const int H = 1 << (s - 1);
        int p = j & (H - 1);
        int r = j >> (s - 1);
        int i0 = r * 4 * H + p;
        c32 e0 = X[i0], e1 = X[i0 + H], e2 = X[i0 + 2 * H], e3 = X[i0 + 3 * H];
        c32 w = tw[p << (8 - s)];
        float wy = conjf * w.y;
        c32 t = make_float2(w.x * e1.x - wy * e1.y, w.x * e1.y + wy * e1.x);
        c32 a0 = make_float2(e0.x + t.x, e0.y + t.y);
        c32 a1 = make_float2(e0.x - t.x, e0.y - t.y);
        t = make_float2(w.x * e3.x - wy * e3.y, w.x * e3.y + wy * e3.x);
        c32 a2 = make_float2(e2.x + t.x, e2.y + t.y);
        c32 a3 = make_float2(e2.x - t.x, e2.y - t.y);
        c32 w0 = tw[p << (7 - s)];
        c32 w1 = tw[(p + H) << (7 - s)];
        float w0y = conjf * w0.y, w1y = conjf * w1.y;
        t = make_float2(w0.x * a2.x - w0y * a2.y, w0.x * a2.y + w0y * a2.x);
        X[i0]         = make_float2(a0.x + t.x, a0.y + t.y);
        X[i0 + 2 * H] = make_float2(a0.x - t.x, a0.y - t.y);
        t = make_float2(w1.x * a3.x - w1y * a3.y, w1.x * a3.y + w1y * a3.x);
        X[i0 + H]     = make_float2(a1.x + t.x, a1.y + t.y);
        X[i0 + 3 * H] = make_float2(a1.x - t.x, a1.y - t.y);
        wave_sync();
    }
}

// Variant B: two waves per line (1 butterfly/lane/stage, block barriers).
__device__ __forceinline__ void fft256_2w(c32* X, const c32* tw, int lane, float conjf) {
    #pragma unroll
    for (int s = 1; s <= 8; ++s) {
        const int half = 1 << (s - 1);
        int grp = lane >> (s - 1);
        int pos = lane & (half - 1);
        int i0 = (grp << s) + pos;
        int i1 = i0 + half;
        c32 w = tw[pos << (8 - s)];
        float wy = conjf * w.y;
        c32 a = X[i0], cc = X[i1];
        c32 t = make_float2(w.x * cc.x - wy * cc.y, w.x * cc.y + wy * cc.x);
        X[i0] = make_float2(a.x + t.x, a.y + t.y);
        X[i1] = make_float2(a.x - t.x, a.y - t.y);
        __syncthreads();
    }
}

__device__ __forceinline__ void build_tw(c32* tw, int tid) {
    if (tid < 128) {
        float a = -3.14159265358979323846f * (float)tid * (1.0f / 128.0f);
        float sv, cv;
        sincosf(a, &sv, &cv);
        tw[tid] = make_float2(cv, sv);
    }
}

// Row inverse FFT, fused load X = S*pred. grid 1536, 256 thr.
__global__ __launch_bounds__(256) void fft_rows_pre(c32* __restrict__ buf,
        const c32* __restrict__ pred) {
    __shared__ c32 lds[2][256];
    __shared__ c32 tw[128];
    int tid = threadIdx.x;
    build_tw(tw, tid);
    int li = tid >> 7, lane = tid & 127;
    int r = blockIdx.x * 2 + li;
    int coil = r >> 8, y = r & 255;
    c32* rp = buf + (size_t)r * 256;
    c32* X = lds[li];
    #pragma unroll
    for (int e = 0; e < 2; ++e) {
        int n = (e << 7) + lane;
        float s = ((n + y) & 1) ? -1.0f : 1.0f;
        c32 pv = pred[(size_t)coil * HW + y * 256 + n];
        X[__brev((unsigned)n) >> 24] = make_float2(s * pv.x, s * pv.y);
    }
    __syncthreads();
    fft256_2w(X, tw, lane, -1.0f);
    #pragma unroll
    for (int e = 0; e < 2; ++e) {
        int n = (e << 7) + lane;
        rp[n] = X[n];
    }
}

// Row forward FFT, fused load X = S*eta*sense. grid 1536, 256 thr. (init only)
__global__ __launch_bounds__(256) void fft_rows_exp(c32* __restrict__ buf,
        const c32* __restrict__ eta, const c32* __restrict__ sense) {
    __shared__ c32 lds[2][256];
    __shared__ c32 tw[128];
    int tid = threadIdx.x;
    build_tw(tw, tid);
    int li = tid >> 7, lane = tid & 127;
    int r = blockIdx.x * 2 + li;
    int coil = r >> 8, y = r & 255;
    c32* rp = buf + (size_t)r * 256;
    c32* X = lds[li];
    #pragma unroll
    for (int e = 0; e < 2; ++e) {
        int n = (e << 7) + lane;
        float s = ((n + y) & 1) ? -1.0f : 1.0f;
        c32 ev = eta[y * 256 + n];
        c32 sn = sense[(size_t)coil * HW + y * 256 + n];
        X[__brev((unsigned)n) >> 24] =
            make_float2(s * (ev.x * sn.x - ev.y * sn.y),
                        s * (ev.x * sn.y + ev.y * sn.x));
    }
    __syncthreads();
    fft256_2w(X, tw, lane, 1.0f);
    #pragma unroll
    for (int e = 0; e < 2; ++e) {
        int n = (e << 7) + lane;
        rp[n] = X[n];
    }
}

// Merged: final conv (eta += d) for row y + forward row FFT of S*eta*sense
// for all 12 coils. grid 256 (1 block/row), 768 thr (12 waves).
__global__ __launch_bounds__(768) void final_exp(const short* __restrict__ hTp,
        const short* __restrict__ wA, c32* __restrict__ eta,
        const c32* __restrict__ sense, c32* __restrict__ buf) {
    __shared__ c32 X[12][256];       // 24 KB
    __shared__ c32 tw[128];
    __shared__ float erx[256], ery[256];
    int tid = threadIdx.x;
    build_tw(tw, tid);
    int wv = tid >> 6, l = tid & 63;
    int lr = l & 15, lg = l >> 4;
    int y = blockIdx.x;

    // ---- final conv: 16 x-tiles over 12 waves ----
    for (int tile = wv; tile < 16; tile += 12) {
        int x = tile * 16 + lr;
        f32x4 C = (f32x4){0.f, 0.f, 0.f, 0.f};
        #pragma unroll
        for (int tap = 0; tap < 9; ++tap) {
            int dy = tap / 3 - 1, dx = tap % 3 - 1;
            const short* pA = wA + (size_t)(tap * 16 + lr) * 64 + lg * 8;
            bf16x8 A0 = *(const bf16x8*)(pA);
            bf16x8 A1 = *(const bf16x8*)(pA + 32);
            const short* pB = hTp +
                ((size_t)((y + dy + 2) * P2 + (x + dx + 2)) << 6) + lg * 8;
            bf16x8 B0 = *(const bf16x8*)(pB);
            bf16x8 B1 = *(const bf16x8*)(pB + 32);
            C = __builtin_amdgcn_mfma_f32_16x16x32_bf16(A0, B0, C, 0, 0, 0);
            C = __builtin_amdgcn_mfma_f32_16x16x32_bf16(A1, B1, C, 0, 0, 0);
        }
        if (lg == 0) {
            int px = y * 256 + x;
            c32 e = eta[px];
            float ex = e.x + C[0], ey = e.y + C[1];
            eta[px] = make_float2(ex, ey);
            erx[x] = ex; ery[x] = ey;
        }
    }
    __syncthreads();   // erow + tw visible to all waves

    // ---- rows_exp: wave = coil, eta from LDS ----
    {
        c32* Xc = &X[wv][0];
        const c32* sn = sense + (size_t)wv * HW + y * 256;
        #pragma unroll
        for (int e = 0; e < 4; ++e) {
            int n = (e << 6) + l;
            float s = ((n + y) & 1) ? -1.0f : 1.0f;
            float ex = erx[n], ey = ery[n];
            c32 sv = sn[n];
            Xc[__brev((unsigned)n) >> 24] =
                make_float2(s * (ex * sv.x - ey * sv.y),
                            s * (ex * sv.y + ey * sv.x));
        }
        wave_sync();
        fft256_wave(Xc, tw, l, 1.0f);
        c32* rp = buf + (size_t)wv * HW + y * 256;
        #pragma unroll
        for (int e = 0; e < 4; ++e) {
            int n = (e << 6) + l;
            rp[n] = Xc[n];
        }
    }
}

// Merged: row-inverse FFT of all 12 coils of row y + coil-combine + g emit.
__global__ __launch_bounds__(768) void fft_rows_grad(const c32* __restrict__ Fk,
        const c32* __restrict__ sense, const c32* __restrict__ eta,
        short* __restrict__ gTp) {
    __shared__ c32 lds[12][256];     // 24 KB
    __shared__ c32 tw[128];
    int tid = threadIdx.x;
    build_tw(tw, tid);
    int wid = tid >> 6, j = tid & 63;
    int y = blockIdx.x;
    {
        const c32* rp = Fk + (size_t)wid * HW + y * 256;
        #pragma unroll
        for (int e = 0; e < 4; ++e) {
            int n = (e << 6) + j;
            lds[wid][__brev((unsigned)n) >> 24] = rp[n];
        }
    }
    __syncthreads();
    fft256_wave(&lds[wid][0], tw, j, -1.0f);
    __syncthreads();
    if (tid < 256) {
        int x = tid;
        int p = y * 256 + x;
        float ax = 0.f, ay = 0.f;
        #pragma unroll
        for (int c = 0; c < NC; ++c) {
            c32 t = lds[c][x];
            c32 s = sense[(size_t)c * HW + p];
            ax += t.x * s.x + t.y * s.y;
            ay += t.y * s.x - t.x * s.y;
        }
        float sc = (((x + y) & 1) ? -1.0f : 1.0f) * (1.0f / 256.0f);
        c32 e = eta[p];
        ushort4 o;
        o.x = (unsigned short)f2bf(e.x);
        o.y = (unsigned short)f2bf(e.y);
        o.z = (unsigned short)f2bf(ax * sc);
        o.w = (unsigned short)f2bf(ay * sc);
        ((ushort4*)gTp)[(y + 2) * P2 + x + 2] = o;
    }
}

// 8-column col FFT (init only). grid (32, NC), 1024 thr.
__global__ __launch_bounds__(1024) void fft_cols(c32* __restrict__ buf, float conjf) {
    __shared__ c32 lds[8][257];
    __shared__ c32 tw[128];
    int tid = threadIdx.x;
    build_tw(tw, tid);
    c32* ip = buf + (size_t)blockIdx.y * HW;
    int x0 = blockIdx.x * 8;
    int xl = tid & 7, yb = tid >> 3;
    #pragma unroll
    for (int e = 0; e < 2; ++e) {
        int y = yb + (e << 7);
        lds[xl][__brev((unsigned)y) >> 24] = ip[y * 256 + x0 + xl];
    }
    __syncthreads();
    int col = tid >> 7, lane = tid & 127;
    fft256_2w(&lds[col][0], tw, lane, conjf);
    #pragma unroll
    for (int e = 0; e < 2; ++e) {
        int y = yb + (e << 7);
        ip[y * 256 + x0 + xl] = lds[xl][y];
    }
}

// 8-column fused: fwd col FFT -> (out + masked residual) -> inv col FFT.
__global__ __launch_bounds__(1024) void fft_cols_fused(c32* __restrict__ buf,
        const c32* __restrict__ base, const c32* __restrict__ ksp,
        const int* __restrict__ mask, c32* __restrict__ outp, int write_out) {
    __shared__ c32 lds[8][257];
    __shared__ c32 tw[128];
    int tid = threadIdx.x;
    build_tw(tw, tid);
    int coil = blockIdx.y;
    c32* ip = buf + (size_t)coil * HW;
    int x0 = blockIdx.x * 8;
    int xl = tid & 7, yb = tid >> 3;
    #pragma unroll
    for (int e = 0; e < 2; ++e) {
        int y = yb + (e << 7);
        lds[xl][__brev((unsigned)y) >> 24] = ip[y * 256 + x0 + xl];
    }
    __syncthreads();
    int col = tid >> 7, lane = tid & 127;
    fft256_2w(&lds[col][0], tw, lane, 1.0f);

    int x = x0 + xl;
    c32 G[2];
    #pragma unroll
    for (int e = 0; e < 2; ++e) {
        int y = yb + (e << 7);
        G[e] = lds[xl][y];
    }
    __syncthreads();
    #pragma unroll
    for (int e = 0; e < 2; ++e) {
        int y = yb + (e << 7);
        int p = y * 256 + x;
        size_t i = (size_t)coil * HW + p;
        float s = ((p ^ (p >> 8)) & 1) ? -1.0f : 1.0f;
        if (write_out) {
            c32 bv = base[i];
            float sc = s * (1.0f / 256.0f);
            outp[i] = make_float2(bv.x - sc * G[e].x, bv.y - sc * G[e].y);
        }
        c32 rv = make_float2(0.f, 0.f);
        if (mask[p]) {
            c32 k = ksp[i];
            rv = make_float2(G[e].x * (1.0f / 256.0f) - s * k.x,
                             G[e].y * (1.0f / 256.0f) - s * k.y);
        }
        lds[xl][__brev((unsigned)y) >> 24] = rv;
    }
    __syncthreads();
    fft256_2w(&lds[col][0], tw, lane, -1.0f);
    #pragma unroll
    for (int e = 0; e < 2; ++e) {
        int y = yb + (e << 7);
        ip[y * 256 + x0 + xl] = lds[xl][y];
    }
}

// ===================== pointwise kernels =====================
__global__ __launch_bounds__(256) void k_combine_eta0(const c32* __restrict__ tmp,
        const c32* __restrict__ sense, c32* __restrict__ eta) {
    int p = blockIdx.x * 256 + threadIdx.x;
    float ax = 0.f, ay = 0.f;
    for (int c = 0; c < NC; ++c) {
        c32 t = tmp[c * HW + p], s = sense[c * HW + p];
        ax += t.x * s.x + t.y * s.y;
        ay += t.y * s.x - t.x * s.y;
    }
    float sc = ssign(p) * (1.0f / 256.0f);
    eta[p] = make_float2(ax * sc, ay * sc);
}

__global__ __launch_bounds__(256) void k_base(const c32* __restrict__ ksp,
        const c32* __restrict__ pred, const int* __restrict__ mask,
        const float* __restrict__ dcw, c32* __restrict__ base) {
    int i = blockIdx.x * 256 + threadIdx.x;
    int p = i & (HW - 1);
    c32 k = ksp[i];
    c32 o = k;
    if (mask[p]) {
        float w = dcw[0];
        c32 pr = pred[i];
        o.x -= (pr.x - k.x) * w;
        o.y -= (pr.y - k.y) * w;
    }
    base[i] = o;
}

__global__ __launch_bounds__(256) void k_zero_border(short* __restrict__ gTp,
        short* __restrict__ h1a, short* __restrict__ h1b,
        short* __restrict__ h2a, short* __restrict__ h2b) {
    int i = blockIdx.x * 256 + threadIdx.x;
    if (i >= 2064) return;
    int y, x;
    if (i < 1040) {
        int r = i / 260;
        y = (r < 2) ? r : 256 + r;
        x = i % 260;
    } else {
        int j = i - 1040;
        y = 2 + (j >> 2);
        int cix = j & 3;
        x = (cix < 2) ? cix : 256 + cix;
    }
    size_t px = (size_t)y * P2 + x;
    ((ushort4*)gTp)[px] = make_ushort4(0, 0, 0, 0);
    uint4 z = make_uint4(0, 0, 0, 0);
    uint4* p1 = (uint4*)(h1a + (px << 6));
    uint4* p2 = (uint4*)(h1b + (px << 6));
    uint4* p3 = (uint4*)(h2a + (px << 6));
    uint4* p4 = (uint4*)(h2b + (px << 6));
    #pragma unroll
    for (int e = 0; e < 8; ++e) { p1[e] = z; p2[e] = z; p3[e] = z; p4[e] = z; }
}

// ===================== weight prep kernels =====================
__global__ __launch_bounds__(256) void k_prep_c1(const float* __restrict__ w,
        short* __restrict__ wA) {
    int i = blockIdx.x * 256 + threadIdx.x;
    int co = i >> 7, k = i & 127;
    int tap = k >> 2, ci = k & 3;
    float v = (tap < 25) ? w[co * 100 + ci * 25 + tap] : 0.f;
    wA[i] = f2bf(v);
}

__global__ __launch_bounds__(256) void k_prep_c2(const float* __restrict__ w,
        short* __restrict__ wA) {
    int i = blockIdx.x * 256 + threadIdx.x;
    int tap = i >> 12, co = (i >> 6) & 63, ci = i & 63;
    wA[i] = f2bf(w[co * 576 + ci * 9 + tap]);
}

__global__ __launch_bounds__(256) void k_prep_cf(const float* __restrict__ w,
        short* __restrict__ wA) {
    int i = blockIdx.x * 256 + threadIdx.x;
    int tap = i >> 10, r = (i >> 6) & 15, ci = i & 63;
    float v = (r < 2) ? w[r * 576 + ci * 9 + tap] : 0.f;
    wA[i] = f2bf(v);
}

__global__ __launch_bounds__(128) void k_prep_gru(const float* __restrict__ ihw,
        const float* __restrict__ ihb, const float* __restrict__ hhw,
        const float* __restrict__ hhb, short* __restrict__ w2, float* __restrict__ bias) {
    int k = threadIdx.x;
    int r = blockIdx.x;
    int g = r >> 6, co = r & 63;
    float v = 0.f;
    if (g == 0)      v = (k < 64) ? ihw[co * 64 + k]         : hhw[co * 64 + k - 64];
    else if (g == 1) v = (k < 64) ? ihw[(64 + co) * 64 + k]  : hhw[(64 + co) * 64 + k - 64];
    else if (g == 2) v = (k < 64) ? ihw[(128 + co) * 64 + k] : 0.f;
    else             v = (k < 64) ? 0.f : hhw[(128 + co) * 64 + k - 64];
    w2[r * 128 + k] = f2bf(v);
    if (k == 0) {
        float b = (g == 0) ? ihb[co] + hhb[co]
                : (g == 1) ? ihb[64 + co] + hhb[64 + co]
                : (g == 2) ? ihb[128 + co] : hhb[128 + co];
        bias[r] = b;
    }
}

// ===================== shared GRU tail (x from LDS, h from global) =========
template <int NTN, bool FIRST>
__device__ __forceinline__ void gru_tail(const short (*xch)[68],
        const short* __restrict__ hprev, const short* __restrict__ w2,
        const float* __restrict__ bias, short* __restrict__ hnext,
        int wv, int lr, int lg, int px0) {
    bf16x8 A0[4], A1[4], A2[2], A3[2];
    {
        const short* w0 = w2 + (0   + wv * 16 + lr) * 128 + lg * 8;
        const short* w1 = w2 + (64  + wv * 16 + lr) * 128 + lg * 8;
        const short* w2p = w2 + (128 + wv * 16 + lr) * 128 + lg * 8;
        const short* w3 = w2 + (192 + wv * 16 + lr) * 128 + lg * 8;
        #pragma unroll
        for (int kt = 0; kt < 4; ++kt) {
            A0[kt] = *(const bf16x8*)(w0 + kt * 32);
            A1[kt] = *(const bf16x8*)(w1 + kt * 32);
        }
        A2[0] = *(const bf16x8*)(w2p);          A2[1] = *(const bf16x8*)(w2p + 32);
        A3[0] = *(const bf16x8*)(w3 + 64);      A3[1] = *(const bf16x8*)(w3 + 96);
    }

    f32x4 C0[NTN], C1[NTN], C2[NTN], C3[NTN];
    #pragma unroll
    for (int nt = 0; nt < NTN; ++nt) {
        C0[nt] = (f32x4){0.f, 0.f, 0.f, 0.f};
        C1[nt] = (f32x4){0.f, 0.f, 0.f, 0.f};
        C2[nt] = (f32x4){0.f, 0.f, 0.f, 0.f};
        C3[nt] = (f32x4){0.f, 0.f, 0.f, 0.f};
    }

    #pragma unroll
    for (int nt = 0; nt < NTN; ++nt) {
        int pxl = nt * 16 + lr;
        int px = px0 + pxl;
        int yy = px >> 8, xx = px & 255;
        size_t pb = ((size_t)((yy + 2) * P2 + (xx + 2)) << 6);
        bf16x8 B0 = *(const bf16x8*)&xch[pxl][lg * 8];
        bf16x8 B1 = *(const bf16x8*)&xch[pxl][32 + lg * 8];
        C0[nt] = __builtin_amdgcn_mfma_f32_16x16x32_bf16(A0[0], B0, C0[nt], 0, 0, 0);
        C0[nt] = __builtin_amdgcn_mfma_f32_16x16x32_bf16(A0[1], B1, C0[nt], 0, 0, 0);
        C1[nt] = __builtin_amdgcn_mfma_f32_16x16x32_bf16(A1[0], B0, C1[nt], 0, 0, 0);
        C1[nt] = __builtin_amdgcn_mfma_f32_16x16x32_bf16(A1[1], B1, C1[nt], 0, 0, 0);
        C2[nt] = __builtin_amdgcn_mfma_f32_16x16x32_bf16(A2[0], B0, C2[nt], 0, 0, 0);
        C2[nt] = __builtin_amdgcn_mfma_f32_16x16x32_bf16(A2[1], B1, C2[nt], 0, 0, 0);
        if (!FIRST) {
            bf16x8 B2 = *(const bf16x8*)(hprev + pb + lg * 8);
            bf16x8 B3 = *(const bf16x8*)(hprev + pb + 32 + lg * 8);
            C0[nt] = __builtin_amdgcn_mfma_f32_16x16x32_bf16(A0[2], B2, C0[nt], 0, 0, 0);
            C0[nt] = __builtin_amdgcn_mfma_f32_16x16x32_bf16(A0[3], B3, C0[nt], 0, 0, 0);
            C1[nt] = __builtin_amdgcn_mfma_f32_16x16x32_bf16(A1[2], B2, C1[nt], 0, 0, 0);
            C1[nt] = __builtin_amdgcn_mfma_f32_16x16x32_bf16(A1[3], B3, C1[nt], 0, 0, 0);
            C3[nt] = __builtin_amdgcn_mfma_f32_16x16x32_bf16(A3[0], B2, C3[nt], 0, 0, 0);
            C3[nt] = __builtin_amdgcn_mfma_f32_16x16x32_bf16(A3[1], B3, C3[nt], 0, 0, 0);
        }
    }

    int co = wv * 16 + lg * 4;
    float br[4], bz[4], bin_[4], bhn[4];
    #pragma unroll
    for (int i = 0; i < 4; ++i) {
        br[i]   = bias[co + i];
        bz[i]   = bias[64 + co + i];
        bin_[i] = bias[128 + co + i];
        bhn[i]  = bias[192 + co + i];
    }
    #pragma unroll
    for (int nt = 0; nt < NTN; ++nt) {
        int px = px0 + nt * 16 + lr;
        int yy = px >> 8, xx = px & 255;
        size_t pb = ((size_t)((yy + 2) * P2 + (xx + 2)) << 6);
        ushort4 hov = make_ushort4(0, 0, 0, 0);
        if (!FIRST) hov = *(const ushort4*)(hprev + pb + co);
        float ho[4] = {bf2f(hov.x), bf2f(hov.y), bf2f(hov.z), bf2f(hov.w)};
        ushort4 st;
        unsigned short* sp = &st.x;
        #pragma unroll
        for (int i = 0; i < 4; ++i) {
            float r = 1.0f / (1.0f + expf(-(C0[nt][i] + br[i])));
            float z = 1.0f / (1.0f + expf(-(C1[nt][i] + bz[i])));
            float nn = tanhf(C2[nt][i] + bin_[i] + r * (C3[nt][i] + bhn[i]));
            float hv = FIRST ? (1.0f - z) * nn : (1.0f - z) * nn + z * ho[i];
            sp[i] = (unsigned short)f2bf(hv);
        }
        *(ushort4*)(hnext + pb + co) = st;
    }
}

// ===================== conv1 + gru1 fused =====================
template <bool FIRST>
__global__ __launch_bounds__(256, 2) void conv1_gru1(const short* __restrict__ gTp,
        const short* __restrict__ wA, const float* __restrict__ cbias,
        const short* __restrict__ w2, const float* __restrict__ gbias,
        const short* __restrict__ hprev, short* __restrict__ hnext) {
    __shared__ short xch[32][68];
    int wv = threadIdx.x >> 6, l = threadIdx.x & 63;
    int lr = l & 15, lg = l >> 4;
    int y = blockIdx.x >> 3;
    int x0 = (blockIdx.x & 7) << 5;

    bf16x8 A[4];
    const short* pA = wA + (size_t)(wv * 16 + lr) * 128 + lg * 8;
    #pragma unroll
    for (int kt = 0; kt < 4; ++kt) A[kt] = *(const bf16x8*)(pA + kt * 32);

    bf16x8 B[2][4];
    #pragma unroll
    for (int nt = 0; nt < 2; ++nt) {
        int x = x0 + nt * 16 + lr;
        #pragma unroll
        for (int kt = 0; kt < 4; ++kt) {
            int t0 = kt * 8 + lg * 2;
            #pragma unroll
            for (int half = 0; half < 2; ++half) {
                int tap = t0 + half;
                int tt = (tap < 25) ? tap : 0;
                int dy = tt / 5 - 2, dx = tt % 5 - 2;
                ushort4 v = *(const ushort4*)(gTp +
                    ((size_t)((y + dy + 2) * P2 + (x + dx + 2)) << 2));
                B[nt][kt][half * 4 + 0] = (short)v.x;
                B[nt][kt][half * 4 + 1] = (short)v.y;
                B[nt][kt][half * 4 + 2] = (short)v.z;
                B[nt][kt][half * 4 + 3] = (short)v.w;
            }
        }
    }
    int co = wv * 16 + lg * 4;
    #pragma unroll
    for (int nt = 0; nt < 2; ++nt) {
        f32x4 C = (f32x4){0.f, 0.f, 0.f, 0.f};
        #pragma unroll
        for (int kt = 0; kt < 4; ++kt)
            C = __builtin_amdgcn_mfma_f32_16x16x32_bf16(A[kt], B[nt][kt], C, 0, 0, 0);
        ushort4 st;
        st.x = (unsigned short)f2bf(fmaxf(C[0] + cbias[co + 0], 0.f));
        st.y = (unsigned short)f2bf(fmaxf(C[1] + cbias[co + 1], 0.f));
        st.z = (unsigned short)f2bf(fmaxf(C[2] + cbias[co + 2], 0.f));
        st.w = (unsigned short)f2bf(fmaxf(C[3] + cbias[co + 3], 0.f));
        *(ushort4*)&xch[nt * 16 + lr][co] = st;
    }
    __syncthreads();

    gru_tail<2, FIRST>(xch, hprev, w2, gbias, hnext, wv, lr, lg, y * 256 + x0);
}

// ===================== conv2 + gru2 fused =====================
template <bool FIRST>
__global__ __launch_bounds__(256, 2) void conv2_gru2(const short* __restrict__ h1Tp,
        const short* __restrict__ wA, const float* __restrict__ cbias,
        const short* __restrict__ w2, const float* __restrict__ gbias,
        const short* __restrict__ hprev, short* __restrict__ hnext) {
    __shared__ uint4 Ld[3][68][9];       // 29376 B
    __shared__ short xch[64][68];        // 8704 B
    int tid = threadIdx.x;
    int wv = tid >> 6, l = tid & 63;
    int lr = l & 15, lg = l >> 4;
    int y = blockIdx.x >> 2;
    int x0 = (blockIdx.x & 3) << 6;

    for (int n = tid; n < 3 * 68 * 8; n += 256) {
        int r = n / (68 * 8);
        int rem = n - r * (68 * 8);
        int px = rem >> 3, e = rem & 7;
        const uint4* src = (const uint4*)(h1Tp +
            (((size_t)(y + 2 * r) * P2 + (x0 + px)) << 6)) + e;
        Ld[r][px][e] = *src;
    }
    __syncthreads();

    f32x4 C[4];
    #pragma unroll
    for (int nt = 0; nt < 4; ++nt) C[nt] = (f32x4){0.f, 0.f, 0.f, 0.f};

    #pragma unroll
    for (int tap = 0; tap < 9; ++tap) {
        int r = tap / 3;
        int dx = (tap % 3 - 1) * 2;
        const short* pA = wA + (size_t)(tap * 64 + wv * 16 + lr) * 64 + lg * 8;
        bf16x8 A0 = *(const bf16x8*)(pA);
        bf16x8 A1 = *(const bf16x8*)(pA + 32);
        #pragma unroll
        for (int nt = 0; nt < 4; ++nt) {
            int xl = nt * 16 + lr + dx + 2;
            bf16x8 B0 = *(const bf16x8*)&Ld[r][xl][lg];
            bf16x8 B1 = *(const bf16x8*)&Ld[r][xl][4 + lg];
            C[nt] = __builtin_amdgcn_mfma_f32_16x16x32_bf16(A0, B0, C[nt], 0, 0, 0);
            C[nt] = __builtin_amdgcn_mfma_f32_16x16x32_bf16(A1, B1, C[nt], 0, 0, 0);
        }
    }
    int co = wv * 16 + lg * 4;
    #pragma unroll
    for (int nt = 0; nt < 4; ++nt) {
        ushort4 st;
        st.x = (unsigned short)f2bf(fmaxf(C[nt][0] + cbias[co + 0], 0.f));
        st.y = (unsigned short)f2bf(fmaxf(C[nt][1] + cbias[co + 1], 0.f));
        st.z = (unsigned short)f2bf(fmaxf(C[nt][2] + cbias[co + 2], 0.f));
        st.w = (unsigned short)f2bf(fmaxf(C[nt][3] + cbias[co + 3], 0.f));
        *(ushort4*)&xch[nt * 16 + lr][co] = st;
    }
    __syncthreads();

    gru_tail<4, FIRST>(xch, hprev, w2, gbias, hnext, wv, lr, lg, y * 256 + x0);
}

// ===================== host orchestration =====================
extern "C" void kernel_launch(void* const* d_in, const int* in_sizes, int n_in,
                              void* d_out, int out_size, void* d_ws, size_t ws_size,
                              hipStream_t stream) {
    const c32* pred   = (const c32*)d_in[0];
    const c32* ksp    = (const c32*)d_in[1];
    const c32* sense  = (const c32*)d_in[2];
    const int* mask   = (const int*)d_in[3];
    const float* c1w  = (const float*)d_in[4];
    const float* c1b  = (const float*)d_in[5];
    const float* g1iw = (const float*)d_in[6];
    const float* g1ib = (const float*)d_in[7];
    const float* g1hw = (const float*)d_in[8];
    const float* g1hb = (const float*)d_in[9];
    const float* c2w  = (const float*)d_in[10];
    const float* c2b  = (const float*)d_in[11];
    const float* g2iw = (const float*)d_in[12];
    const float* g2ib = (const float*)d_in[13];
    const float* g2hw = (const float*)d_in[14];
    const float* g2hb = (const float*)d_in[15];
    const float* fw   = (const float*)d_in[16];
    const float* dcw  = (const float*)d_in[17];

    const size_t PP = (size_t)P2 * P2;     // 67600 padded pixels
    float* w0 = (float*)d_ws;
    c32* base = (c32*)w0;                  // NC*HW complex
    c32* Fk   = base + NC * HW;            // NC*HW complex
    c32* tmp  = Fk + NC * HW;              // NC*HW complex (init only)
    c32* eta  = tmp + NC * HW;             // HW complex
    short* gTp = (short*)(eta + HW);       // PP*4 bf16 (padded)
    short* h1Ta = gTp + PP * 4;            // PP*64 bf16 (padded)
    short* h1Tb = h1Ta + PP * 64;
    short* h2Ta = h1Tb + PP * 64;
    short* h2Tb = h2Ta + PP * 64;
    short* w2a  = h2Tb + PP * 64;          // 256*128 bf16
    short* w2b  = w2a + 256 * 128;
    float* biasA = (float*)(w2b + 256 * 128);
    float* biasB = biasA + 256;
    short* wAc2 = (short*)(biasB + 256);   // 9*64*64 bf16
    short* wAc1 = wAc2 + 9 * 64 * 64;      // 64*128 bf16
    short* wAcf = wAc1 + 64 * 128;         // 9*16*64 bf16

    dim3 B(256);
    const int gCHW = NC * HW / 256;   // 3072
    const int gHW  = HW / 256;        // 256
    const int gROW = NC * 256 / 2;    // 1536 (2 rows/block)
    dim3 gCOL(32, NC);                // 8-col tiles, 1024 thr
    dim3 B1024(1024);
    dim3 B768(768);
    const int gC1 = HW / 32;          // 2048 blocks (conv1+gru1)
    const int gC2 = HW / 64;          // 1024 blocks (conv2+gru2)

    // border zeroing + weight prep (once per call)
    k_zero_border<<<9, B, 0, stream>>>(gTp, h1Ta, h1Tb, h2Ta, h2Tb);
    k_prep_gru<<<256, 128, 0, stream>>>(g1iw, g1ib, g1hw, g1hb, w2a, biasA);
    k_prep_gru<<<256, 128, 0, stream>>>(g2iw, g2ib, g2hw, g2hb, w2b, biasB);
    k_prep_c2<<<144, 256, 0, stream>>>(c2w, wAc2);
    k_prep_c1<<<32, 256, 0, stream>>>(c1w, wAc1);
    k_prep_cf<<<36, 256, 0, stream>>>(fw, wAcf);

    // eta0 = sum_c ifft2c(pred_c) * conj(sense_c)
    fft_rows_pre<<<gROW, B, 0, stream>>>(tmp, pred);
    fft_cols<<<gCOL, B1024, 0, stream>>>(tmp, -1.0f);
    k_combine_eta0<<<gHW, B, 0, stream>>>(tmp, sense, eta);

    k_base<<<gCHW, B, 0, stream>>>(ksp, pred, mask, dcw, base);

    // F_0: forward FFT of S*(eta0*sense); fused epilogue -> residual (no out)
    fft_rows_exp<<<gROW, B, 0, stream>>>(Fk, eta, sense);
    fft_cols_fused<<<gCOL, B1024, 0, stream>>>(Fk, base, ksp, mask, (c32*)d_out, 0);

    short* h1c = h1Ta; short* h1n = h1Tb;
    short* h2c = h2Ta; short* h2n = h2Tb;
    c32* outp = (c32*)d_out;

    for (int t = 0; t < NT; ++t) {
        fft_rows_grad<<<gHW, B768, 0, stream>>>(Fk, sense, eta, gTp);

        if (t == 0) {
            conv1_gru1<true><<<gC1, B, 0, stream>>>(gTp, wAc1, c1b, w2a, biasA, h1c, h1n);
        } else {
            conv1_gru1<false><<<gC1, B, 0, stream>>>(gTp, wAc1, c1b, w2a, biasA, h1c, h1n);
        }
        { short* s = h1c; h1c = h1n; h1n = s; }
        if (t == 0) {
            conv2_gru2<true><<<gC2, B, 0, stream>>>(h1c, wAc2, c2b, w2b, biasB, h2c, h2n);
        } else {
            conv2_gru2<false><<<gC2, B, 0, stream>>>(h1c, wAc2, c2b, w2b, biasB, h2c, h2n);
        }
        { short* s = h2c; h2c = h2n; h2n = s; }

        // merged: final conv (eta += d) + forward row FFT of S*eta*sense
        final_exp<<<gHW, B768, 0, stream>>>(h2c, wAcf, eta, sense, Fk);

        fft_cols_fused<<<gCOL, B1024, 0, stream>>>(Fk, base, ksp, mask,
                                                   outp + (size_t)t * NC * HW, 1);
    }
}

// Round 19
// 847.037 us; speedup vs baseline: 1.0693x; 1.0070x over previous
//
#include <hip/hip_runtime.h>

#define HW 65536
#define NC 12
#define NF 64
#define NT 8
#define P2 260   // padded pitch (2-wide zero border each side)

typedef float2 c32;
typedef __attribute__((ext_vector_type(8))) short bf16x8;   // 8 bf16 = 4 VGPR
typedef __attribute__((ext_vector_type(4))) float f32x4;    // MFMA C/D

__device__ __forceinline__ float ssign(int p) {
    return ((p ^ (p >> 8)) & 1) ? -1.0f : 1.0f;
}

__device__ __forceinline__ short f2bf(float f) {   // RNE float->bf16
    union { float f; unsigned u; } v; v.f = f;
    unsigned r = (v.u + 0x7FFFu + ((v.u >> 16) & 1u)) >> 16;
    return (short)r;
}

__device__ __forceinline__ float bf2f(unsigned short u) {
    union { unsigned u; float f; } v; v.u = (unsigned)u << 16;
    return v.f;
}

__device__ __forceinline__ unsigned pack_bf(float x, float y) {
    return (unsigned)(unsigned short)f2bf(x) |
           ((unsigned)(unsigned short)f2bf(y) << 16);
}

__device__ __forceinline__ c32 unpack_bf(unsigned u) {
    return make_float2(bf2f((unsigned short)(u & 0xffff)),
                       bf2f((unsigned short)(u >> 16)));
}

// ===================== 256-point FFT =====================
__device__ __forceinline__ void wave_sync() {
    asm volatile("s_waitcnt lgkmcnt(0)" ::: "memory");
}

// Variant A: one wave per line (stage-pairs, 4 syncs).
__device__ __forceinline__ void fft256_wave(c32* X, const c32* tw, int j, float conjf) {
    #pragma unroll
    for (int s = 1; s <= 8; s += 2) {
        const int H = 1 << (s - 1);
        int p = j & (H - 1);
        int r = j >> (s - 1);
        int i0 = r * 4 * H + p;
        c32 e0 = X[i0], e1 = X[i0 + H], e2 = X[i0 + 2 * H], e3 = X[i0 + 3 * H];
        c32 w = tw[p << (8 - s)];
        float wy = conjf * w.y;
        c32 t = make_float2(w.x * e1.x - wy * e1.y, w.x * e1.y + wy * e1.x);
        c32 a0 = make_float2(e0.x + t.x, e0.y + t.y);
        c32 a1 = make_float2(e0.x - t.x, e0.y - t.y);
        t = make_float2(w.x * e3.x - wy * e3.y, w.x * e3.y + wy * e3.x);
        c32 a2 = make_float2(e2.x + t.x, e2.y + t.y);
        c32 a3 = make_float2(e2.x - t.x, e2.y - t.y);
        c32 w0 = tw[p << (7 - s)];
        c32 w1 = tw[(p + H) << (7 - s)];
        float w0y = conjf * w0.y, w1y = conjf * w1.y;
        t = make_float2(w0.x * a2.x - w0y * a2.y, w0.x * a2.y + w0y * a2.x);
        X[i0]         = make_float2(a0.x + t.x, a0.y + t.y);
        X[i0 + 2 * H] = make_float2(a0.x - t.x, a0.y - t.y);
        t = make_float2(w1.x * a3.x - w1y * a3.y, w1.x * a3.y + w1y * a3.x);
        X[i0 + H]     = make_float2(a1.x + t.x, a1.y + t.y);
        X[i0 + 3 * H] = make_float2(a1.x - t.x, a1.y - t.y);
        wave_sync();
    }
}

// Variant B: two waves per line (1 butterfly/lane/stage, block barriers).
__device__ __forceinline__ void fft256_2w(c32* X, const c32* tw, int lane, float conjf) {
    #pragma unroll
    for (int s = 1; s <= 8; ++s) {
        const int half = 1 << (s - 1);
        int grp = lane >> (s - 1);
        int pos = lane & (half - 1);
        int i0 = (grp << s) + pos;
        int i1 = i0 + half;
        c32 w = tw[pos << (8 - s)];
        float wy = conjf * w.y;
        c32 a = X[i0], cc = X[i1];
        c32 t = make_float2(w.x * cc.x - wy * cc.y, w.x * cc.y + wy * cc.x);
        X[i0] = make_float2(a.x + t.x, a.y + t.y);
        X[i1] = make_float2(a.x - t.x, a.y - t.y);
        __syncthreads();
    }
}

__device__ __forceinline__ void build_tw(c32* tw, int tid) {
    if (tid < 128) {
        float a = -3.14159265358979323846f * (float)tid * (1.0f / 128.0f);
        float sv, cv;
        sincosf(a, &sv, &cv);
        tw[tid] = make_float2(cv, sv);
    }
}

// Row inverse FFT, fused load X = S*pred. grid 1536, 256 thr. (init, fp32)
__global__ __launch_bounds__(256) void fft_rows_pre(c32* __restrict__ buf,
        const c32* __restrict__ pred) {
    __shared__ c32 lds[2][256];
    __shared__ c32 tw[128];
    int tid = threadIdx.x;
    build_tw(tw, tid);
    int li = tid >> 7, lane = tid & 127;
    int r = blockIdx.x * 2 + li;
    int coil = r >> 8, y = r & 255;
    c32* rp = buf + (size_t)r * 256;
    c32* X = lds[li];
    #pragma unroll
    for (int e = 0; e < 2; ++e) {
        int n = (e << 7) + lane;
        float s = ((n + y) & 1) ? -1.0f : 1.0f;
        c32 pv = pred[(size_t)coil * HW + y * 256 + n];
        X[__brev((unsigned)n) >> 24] = make_float2(s * pv.x, s * pv.y);
    }
    __syncthreads();
    fft256_2w(X, tw, lane, -1.0f);
    #pragma unroll
    for (int e = 0; e < 2; ++e) {
        int n = (e << 7) + lane;
        rp[n] = X[n];
    }
}

// Row forward FFT, fused load X = S*eta*sense -> packed bf16 Fk. (init only)
__global__ __launch_bounds__(256) void fft_rows_exp(unsigned* __restrict__ buf,
        const c32* __restrict__ eta, const c32* __restrict__ sense) {
    __shared__ c32 lds[2][256];
    __shared__ c32 tw[128];
    int tid = threadIdx.x;
    build_tw(tw, tid);
    int li = tid >> 7, lane = tid & 127;
    int r = blockIdx.x * 2 + li;
    int coil = r >> 8, y = r & 255;
    unsigned* rp = buf + (size_t)r * 256;
    c32* X = lds[li];
    #pragma unroll
    for (int e = 0; e < 2; ++e) {
        int n = (e << 7) + lane;
        float s = ((n + y) & 1) ? -1.0f : 1.0f;
        c32 ev = eta[y * 256 + n];
        c32 sn = sense[(size_t)coil * HW + y * 256 + n];
        X[__brev((unsigned)n) >> 24] =
            make_float2(s * (ev.x * sn.x - ev.y * sn.y),
                        s * (ev.x * sn.y + ev.y * sn.x));
    }
    __syncthreads();
    fft256_2w(X, tw, lane, 1.0f);
    #pragma unroll
    for (int e = 0; e < 2; ++e) {
        int n = (e << 7) + lane;
        rp[n] = pack_bf(X[n].x, X[n].y);
    }
}

// Merged: final conv (eta += d) for row y + forward row FFT of S*eta*sense.
// grid 256, 768 thr. Fk packed bf16; sense packed bf16.
__global__ __launch_bounds__(768) void final_exp(const short* __restrict__ hTp,
        const short* __restrict__ wA, c32* __restrict__ eta,
        const unsigned* __restrict__ senseb, unsigned* __restrict__ buf) {
    __shared__ c32 X[12][256];       // 24 KB
    __shared__ c32 tw[128];
    __shared__ float erx[256], ery[256];
    int tid = threadIdx.x;
    build_tw(tw, tid);
    int wv = tid >> 6, l = tid & 63;
    int lr = l & 15, lg = l >> 4;
    int y = blockIdx.x;

    // ---- final conv: 16 x-tiles over 12 waves ----
    for (int tile = wv; tile < 16; tile += 12) {
        int x = tile * 16 + lr;
        f32x4 C = (f32x4){0.f, 0.f, 0.f, 0.f};
        #pragma unroll
        for (int tap = 0; tap < 9; ++tap) {
            int dy = tap / 3 - 1, dx = tap % 3 - 1;
            const short* pA = wA + (size_t)(tap * 16 + lr) * 64 + lg * 8;
            bf16x8 A0 = *(const bf16x8*)(pA);
            bf16x8 A1 = *(const bf16x8*)(pA + 32);
            const short* pB = hTp +
                ((size_t)((y + dy + 2) * P2 + (x + dx + 2)) << 6) + lg * 8;
            bf16x8 B0 = *(const bf16x8*)(pB);
            bf16x8 B1 = *(const bf16x8*)(pB + 32);
            C = __builtin_amdgcn_mfma_f32_16x16x32_bf16(A0, B0, C, 0, 0, 0);
            C = __builtin_amdgcn_mfma_f32_16x16x32_bf16(A1, B1, C, 0, 0, 0);
        }
        if (lg == 0) {
            int px = y * 256 + x;
            c32 e = eta[px];
            float ex = e.x + C[0], ey = e.y + C[1];
            eta[px] = make_float2(ex, ey);
            erx[x] = ex; ery[x] = ey;
        }
    }
    __syncthreads();

    // ---- rows_exp: wave = coil, eta from LDS, sense bf16 ----
    {
        c32* Xc = &X[wv][0];
        const unsigned* sn = senseb + (size_t)wv * HW + y * 256;
        #pragma unroll
        for (int e = 0; e < 4; ++e) {
            int n = (e << 6) + l;
            float s = ((n + y) & 1) ? -1.0f : 1.0f;
            float ex = erx[n], ey = ery[n];
            c32 sv = unpack_bf(sn[n]);
            Xc[__brev((unsigned)n) >> 24] =
                make_float2(s * (ex * sv.x - ey * sv.y),
                            s * (ex * sv.y + ey * sv.x));
        }
        wave_sync();
        fft256_wave(Xc, tw, l, 1.0f);
        unsigned* rp = buf + (size_t)wv * HW + y * 256;
        #pragma unroll
        for (int e = 0; e < 4; ++e) {
            int n = (e << 6) + l;
            rp[n] = pack_bf(Xc[n].x, Xc[n].y);
        }
    }
}

// Merged: row-inverse FFT of all 12 coils (packed Fk) + coil-combine + g emit.
__global__ __launch_bounds__(768) void fft_rows_grad(const unsigned* __restrict__ Fk,
        const unsigned* __restrict__ senseb, const c32* __restrict__ eta,
        short* __restrict__ gTp) {
    __shared__ c32 lds[12][256];     // 24 KB
    __shared__ c32 tw[128];
    int tid = threadIdx.x;
    build_tw(tw, tid);
    int wid = tid >> 6, j = tid & 63;
    int y = blockIdx.x;
    {
        const unsigned* rp = Fk + (size_t)wid * HW + y * 256;
        #pragma unroll
        for (int e = 0; e < 4; ++e) {
            int n = (e << 6) + j;
            lds[wid][__brev((unsigned)n) >> 24] = unpack_bf(rp[n]);
        }
    }
    __syncthreads();
    fft256_wave(&lds[wid][0], tw, j, -1.0f);
    __syncthreads();
    if (tid < 256) {
        int x = tid;
        int p = y * 256 + x;
        float ax = 0.f, ay = 0.f;
        #pragma unroll
        for (int c = 0; c < NC; ++c) {
            c32 t = lds[c][x];
            c32 s = unpack_bf(senseb[(size_t)c * HW + p]);
            ax += t.x * s.x + t.y * s.y;
            ay += t.y * s.x - t.x * s.y;
        }
        float sc = (((x + y) & 1) ? -1.0f : 1.0f) * (1.0f / 256.0f);
        c32 e = eta[p];
        ushort4 o;
        o.x = (unsigned short)f2bf(e.x);
        o.y = (unsigned short)f2bf(e.y);
        o.z = (unsigned short)f2bf(ax * sc);
        o.w = (unsigned short)f2bf(ay * sc);
        ((ushort4*)gTp)[(y + 2) * P2 + x + 2] = o;
    }
}

// 8-column col FFT (init only, fp32 tmp). grid (32, NC), 1024 thr.
__global__ __launch_bounds__(1024) void fft_cols(c32* __restrict__ buf, float conjf) {
    __shared__ c32 lds[8][257];
    __shared__ c32 tw[128];
    int tid = threadIdx.x;
    build_tw(tw, tid);
    c32* ip = buf + (size_t)blockIdx.y * HW;
    int x0 = blockIdx.x * 8;
    int xl = tid & 7, yb = tid >> 3;
    #pragma unroll
    for (int e = 0; e < 2; ++e) {
        int y = yb + (e << 7);
        lds[xl][__brev((unsigned)y) >> 24] = ip[y * 256 + x0 + xl];
    }
    __syncthreads();
    int col = tid >> 7, lane = tid & 127;
    fft256_2w(&lds[col][0], tw, lane, conjf);
    #pragma unroll
    for (int e = 0; e < 2; ++e) {
        int y = yb + (e << 7);
        ip[y * 256 + x0 + xl] = lds[xl][y];
    }
}

// 8-column fused: fwd col FFT -> (out + masked residual) -> inv col FFT.
// Fk packed bf16 in/out.
__global__ __launch_bounds__(1024) void fft_cols_fused(unsigned* __restrict__ buf,
        const c32* __restrict__ base, const c32* __restrict__ ksp,
        const int* __restrict__ mask, c32* __restrict__ outp, int write_out) {
    __shared__ c32 lds[8][257];
    __shared__ c32 tw[128];
    int tid = threadIdx.x;
    build_tw(tw, tid);
    int coil = blockIdx.y;
    unsigned* ip = buf + (size_t)coil * HW;
    int x0 = blockIdx.x * 8;
    int xl = tid & 7, yb = tid >> 3;
    #pragma unroll
    for (int e = 0; e < 2; ++e) {
        int y = yb + (e << 7);
        lds[xl][__brev((unsigned)y) >> 24] = unpack_bf(ip[y * 256 + x0 + xl]);
    }
    __syncthreads();
    int col = tid >> 7, lane = tid & 127;
    fft256_2w(&lds[col][0], tw, lane, 1.0f);

    int x = x0 + xl;
    c32 G[2];
    #pragma unroll
    for (int e = 0; e < 2; ++e) {
        int y = yb + (e << 7);
        G[e] = lds[xl][y];
    }
    __syncthreads();
    #pragma unroll
    for (int e = 0; e < 2; ++e) {
        int y = yb + (e << 7);
        int p = y * 256 + x;
        size_t i = (size_t)coil * HW + p;
        float s = ((p ^ (p >> 8)) & 1) ? -1.0f : 1.0f;
        if (write_out) {
            c32 bv = base[i];
            float sc = s * (1.0f / 256.0f);
            outp[i] = make_float2(bv.x - sc * G[e].x, bv.y - sc * G[e].y);
        }
        c32 rv = make_float2(0.f, 0.f);
        if (mask[p]) {
            c32 k = ksp[i];
            rv = make_float2(G[e].x * (1.0f / 256.0f) - s * k.x,
                             G[e].y * (1.0f / 256.0f) - s * k.y);
        }
        lds[xl][__brev((unsigned)y) >> 24] = rv;
    }
    __syncthreads();
    fft256_2w(&lds[col][0], tw, lane, -1.0f);
    #pragma unroll
    for (int e = 0; e < 2; ++e) {
        int y = yb + (e << 7);
        ip[y * 256 + x0 + xl] = pack_bf(lds[xl][y].x, lds[xl][y].y);
    }
}

// ===================== pointwise kernels =====================
__global__ __launch_bounds__(256) void k_combine_eta0(const c32* __restrict__ tmp,
        const c32* __restrict__ sense, c32* __restrict__ eta) {
    int p = blockIdx.x * 256 + threadIdx.x;
    float ax = 0.f, ay = 0.f;
    for (int c = 0; c < NC; ++c) {
        c32 t = tmp[c * HW + p], s = sense[c * HW + p];
        ax += t.x * s.x + t.y * s.y;
        ay += t.y * s.x - t.x * s.y;
    }
    float sc = ssign(p) * (1.0f / 256.0f);
    eta[p] = make_float2(ax * sc, ay * sc);
}

__global__ __launch_bounds__(256) void k_base(const c32* __restrict__ ksp,
        const c32* __restrict__ pred, const int* __restrict__ mask,
        const float* __restrict__ dcw, c32* __restrict__ base) {
    int i = blockIdx.x * 256 + threadIdx.x;
    int p = i & (HW - 1);
    c32 k = ksp[i];
    c32 o = k;
    if (mask[p]) {
        float w = dcw[0];
        c32 pr = pred[i];
        o.x -= (pr.x - k.x) * w;
        o.y -= (pr.y - k.y) * w;
    }
    base[i] = o;
}

// sense -> packed bf16 copy. grid 3072, 256 thr.
__global__ __launch_bounds__(256) void k_prep_sense(const c32* __restrict__ sense,
        unsigned* __restrict__ senseb) {
    int i = blockIdx.x * 256 + threadIdx.x;
    c32 s = sense[i];
    senseb[i] = pack_bf(s.x, s.y);
}

__global__ __launch_bounds__(256) void k_zero_border(short* __restrict__ gTp,
        short* __restrict__ h1a, short* __restrict__ h1b,
        short* __restrict__ h2a, short* __restrict__ h2b) {
    int i = blockIdx.x * 256 + threadIdx.x;
    if (i >= 2064) return;
    int y, x;
    if (i < 1040) {
        int r = i / 260;
        y = (r < 2) ? r : 256 + r;
        x = i % 260;
    } else {
        int j = i - 1040;
        y = 2 + (j >> 2);
        int cix = j & 3;
        x = (cix < 2) ? cix : 256 + cix;
    }
    size_t px = (size_t)y * P2 + x;
    ((ushort4*)gTp)[px] = make_ushort4(0, 0, 0, 0);
    uint4 z = make_uint4(0, 0, 0, 0);
    uint4* p1 = (uint4*)(h1a + (px << 6));
    uint4* p2 = (uint4*)(h1b + (px << 6));
    uint4* p3 = (uint4*)(h2a + (px << 6));
    uint4* p4 = (uint4*)(h2b + (px << 6));
    #pragma unroll
    for (int e = 0; e < 8; ++e) { p1[e] = z; p2[e] = z; p3[e] = z; p4[e] = z; }
}

// ===================== weight prep kernels =====================
__global__ __launch_bounds__(256) void k_prep_c1(const float* __restrict__ w,
        short* __restrict__ wA) {
    int i = blockIdx.x * 256 + threadIdx.x;
    int co = i >> 7, k = i & 127;
    int tap = k >> 2, ci = k & 3;
    float v = (tap < 25) ? w[co * 100 + ci * 25 + tap] : 0.f;
    wA[i] = f2bf(v);
}

__global__ __launch_bounds__(256) void k_prep_c2(const float* __restrict__ w,
        short* __restrict__ wA) {
    int i = blockIdx.x * 256 + threadIdx.x;
    int tap = i >> 12, co = (i >> 6) & 63, ci = i & 63;
    wA[i] = f2bf(w[co * 576 + ci * 9 + tap]);
}

__global__ __launch_bounds__(256) void k_prep_cf(const float* __restrict__ w,
        short* __restrict__ wA) {
    int i = blockIdx.x * 256 + threadIdx.x;
    int tap = i >> 10, r = (i >> 6) & 15, ci = i & 63;
    float v = (r < 2) ? w[r * 576 + ci * 9 + tap] : 0.f;
    wA[i] = f2bf(v);
}

__global__ __launch_bounds__(128) void k_prep_gru(const float* __restrict__ ihw,
        const float* __restrict__ ihb, const float* __restrict__ hhw,
        const float* __restrict__ hhb, short* __restrict__ w2, float* __restrict__ bias) {
    int k = threadIdx.x;
    int r = blockIdx.x;
    int g = r >> 6, co = r & 63;
    float v = 0.f;
    if (g == 0)      v = (k < 64) ? ihw[co * 64 + k]         : hhw[co * 64 + k - 64];
    else if (g == 1) v = (k < 64) ? ihw[(64 + co) * 64 + k]  : hhw[(64 + co) * 64 + k - 64];
    else if (g == 2) v = (k < 64) ? ihw[(128 + co) * 64 + k] : 0.f;
    else             v = (k < 64) ? 0.f : hhw[(128 + co) * 64 + k - 64];
    w2[r * 128 + k] = f2bf(v);
    if (k == 0) {
        float b = (g == 0) ? ihb[co] + hhb[co]
                : (g == 1) ? ihb[64 + co] + hhb[64 + co]
                : (g == 2) ? ihb[128 + co] : hhb[128 + co];
        bias[r] = b;
    }
}

// ===================== shared GRU tail (x from LDS, h from global) =========
template <int NTN, bool FIRST>
__device__ __forceinline__ void gru_tail(const short (*xch)[68],
        const short* __restrict__ hprev, const short* __restrict__ w2,
        const float* __restrict__ bias, short* __restrict__ hnext,
        int wv, int lr, int lg, int px0) {
    bf16x8 A0[4], A1[4], A2[2], A3[2];
    {
        const short* w0 = w2 + (0   + wv * 16 + lr) * 128 + lg * 8;
        const short* w1 = w2 + (64  + wv * 16 + lr) * 128 + lg * 8;
        const short* w2p = w2 + (128 + wv * 16 + lr) * 128 + lg * 8;
        const short* w3 = w2 + (192 + wv * 16 + lr) * 128 + lg * 8;
        #pragma unroll
        for (int kt = 0; kt < 4; ++kt) {
            A0[kt] = *(const bf16x8*)(w0 + kt * 32);
            A1[kt] = *(const bf16x8*)(w1 + kt * 32);
        }
        A2[0] = *(const bf16x8*)(w2p);          A2[1] = *(const bf16x8*)(w2p + 32);
        A3[0] = *(const bf16x8*)(w3 + 64);      A3[1] = *(const bf16x8*)(w3 + 96);
    }

    f32x4 C0[NTN], C1[NTN], C2[NTN], C3[NTN];
    #pragma unroll
    for (int nt = 0; nt < NTN; ++nt) {
        C0[nt] = (f32x4){0.f, 0.f, 0.f, 0.f};
        C1[nt] = (f32x4){0.f, 0.f, 0.f, 0.f};
        C2[nt] = (f32x4){0.f, 0.f, 0.f, 0.f};
        C3[nt] = (f32x4){0.f, 0.f, 0.f, 0.f};
    }

    #pragma unroll
    for (int nt = 0; nt < NTN; ++nt) {
        int pxl = nt * 16 + lr;
        int px = px0 + pxl;
        int yy = px >> 8, xx = px & 255;
        size_t pb = ((size_t)((yy + 2) * P2 + (xx + 2)) << 6);
        bf16x8 B0 = *(const bf16x8*)&xch[pxl][lg * 8];
        bf16x8 B1 = *(const bf16x8*)&xch[pxl][32 + lg * 8];
        C0[nt] = __builtin_amdgcn_mfma_f32_16x16x32_bf16(A0[0], B0, C0[nt], 0, 0, 0);
        C0[nt] = __builtin_amdgcn_mfma_f32_16x16x32_bf16(A0[1], B1, C0[nt], 0, 0, 0);
        C1[nt] = __builtin_amdgcn_mfma_f32_16x16x32_bf16(A1[0], B0, C1[nt], 0, 0, 0);
        C1[nt] = __builtin_amdgcn_mfma_f32_16x16x32_bf16(A1[1], B1, C1[nt], 0, 0, 0);
        C2[nt] = __builtin_amdgcn_mfma_f32_16x16x32_bf16(A2[0], B0, C2[nt], 0, 0, 0);
        C2[nt] = __builtin_amdgcn_mfma_f32_16x16x32_bf16(A2[1], B1, C2[nt], 0, 0, 0);
        if (!FIRST) {
            bf16x8 B2 = *(const bf16x8*)(hprev + pb + lg * 8);
            bf16x8 B3 = *(const bf16x8*)(hprev + pb + 32 + lg * 8);
            C0[nt] = __builtin_amdgcn_mfma_f32_16x16x32_bf16(A0[2], B2, C0[nt], 0, 0, 0);
            C0[nt] = __builtin_amdgcn_mfma_f32_16x16x32_bf16(A0[3], B3, C0[nt], 0, 0, 0);
            C1[nt] = __builtin_amdgcn_mfma_f32_16x16x32_bf16(A1[2], B2, C1[nt], 0, 0, 0);
            C1[nt] = __builtin_amdgcn_mfma_f32_16x16x32_bf16(A1[3], B3, C1[nt], 0, 0, 0);
            C3[nt] = __builtin_amdgcn_mfma_f32_16x16x32_bf16(A3[0], B2, C3[nt], 0, 0, 0);
            C3[nt] = __builtin_amdgcn_mfma_f32_16x16x32_bf16(A3[1], B3, C3[nt], 0, 0, 0);
        }
    }

    int co = wv * 16 + lg * 4;
    float br[4], bz[4], bin_[4], bhn[4];
    #pragma unroll
    for (int i = 0; i < 4; ++i) {
        br[i]   = bias[co + i];
        bz[i]   = bias[64 + co + i];
        bin_[i] = bias[128 + co + i];
        bhn[i]  = bias[192 + co + i];
    }
    #pragma unroll
    for (int nt = 0; nt < NTN; ++nt) {
        int px = px0 + nt * 16 + lr;
        int yy = px >> 8, xx = px & 255;
        size_t pb = ((size_t)((yy + 2) * P2 + (xx + 2)) << 6);
        ushort4 hov = make_ushort4(0, 0, 0, 0);
        if (!FIRST) hov = *(const ushort4*)(hprev + pb + co);
        float ho[4] = {bf2f(hov.x), bf2f(hov.y), bf2f(hov.z), bf2f(hov.w)};
        ushort4 st;
        unsigned short* sp = &st.x;
        #pragma unroll
        for (int i = 0; i < 4; ++i) {
            float r = 1.0f / (1.0f + expf(-(C0[nt][i] + br[i])));
            float z = 1.0f / (1.0f + expf(-(C1[nt][i] + bz[i])));
            float nn = tanhf(C2[nt][i] + bin_[i] + r * (C3[nt][i] + bhn[i]));
            float hv = FIRST ? (1.0f - z) * nn : (1.0f - z) * nn + z * ho[i];
            sp[i] = (unsigned short)f2bf(hv);
        }
        *(ushort4*)(hnext + pb + co) = st;
    }
}

// ===================== conv1 + gru1 fused =====================
template <bool FIRST>
__global__ __launch_bounds__(256, 2) void conv1_gru1(const short* __restrict__ gTp,
        const short* __restrict__ wA, const float* __restrict__ cbias,
        const short* __restrict__ w2, const float* __restrict__ gbias,
        const short* __restrict__ hprev, short* __restrict__ hnext) {
    __shared__ short xch[32][68];
    int wv = threadIdx.x >> 6, l = threadIdx.x & 63;
    int lr = l & 15, lg = l >> 4;
    int y = blockIdx.x >> 3;
    int x0 = (blockIdx.x & 7) << 5;

    bf16x8 A[4];
    const short* pA = wA + (size_t)(wv * 16 + lr) * 128 + lg * 8;
    #pragma unroll
    for (int kt = 0; kt < 4; ++kt) A[kt] = *(const bf16x8*)(pA + kt * 32);

    bf16x8 B[2][4];
    #pragma unroll
    for (int nt = 0; nt < 2; ++nt) {
        int x = x0 + nt * 16 + lr;
        #pragma unroll
        for (int kt = 0; kt < 4; ++kt) {
            int t0 = kt * 8 + lg * 2;
            #pragma unroll
            for (int half = 0; half < 2; ++half) {
                int tap = t0 + half;
                int tt = (tap < 25) ? tap : 0;
                int dy = tt / 5 - 2, dx = tt % 5 - 2;
                ushort4 v = *(const ushort4*)(gTp +
                    ((size_t)((y + dy + 2) * P2 + (x + dx + 2)) << 2));
                B[nt][kt][half * 4 + 0] = (short)v.x;
                B[nt][kt][half * 4 + 1] = (short)v.y;
                B[nt][kt][half * 4 + 2] = (short)v.z;
                B[nt][kt][half * 4 + 3] = (short)v.w;
            }
        }
    }
    int co = wv * 16 + lg * 4;
    #pragma unroll
    for (int nt = 0; nt < 2; ++nt) {
        f32x4 C = (f32x4){0.f, 0.f, 0.f, 0.f};
        #pragma unroll
        for (int kt = 0; kt < 4; ++kt)
            C = __builtin_amdgcn_mfma_f32_16x16x32_bf16(A[kt], B[nt][kt], C, 0, 0, 0);
        ushort4 st;
        st.x = (unsigned short)f2bf(fmaxf(C[0] + cbias[co + 0], 0.f));
        st.y = (unsigned short)f2bf(fmaxf(C[1] + cbias[co + 1], 0.f));
        st.z = (unsigned short)f2bf(fmaxf(C[2] + cbias[co + 2], 0.f));
        st.w = (unsigned short)f2bf(fmaxf(C[3] + cbias[co + 3], 0.f));
        *(ushort4*)&xch[nt * 16 + lr][co] = st;
    }
    __syncthreads();

    gru_tail<2, FIRST>(xch, hprev, w2, gbias, hnext, wv, lr, lg, y * 256 + x0);
}

// ===================== conv2 + gru2 fused =====================
template <bool FIRST>
__global__ __launch_bounds__(256, 2) void conv2_gru2(const short* __restrict__ h1Tp,
        const short* __restrict__ wA, const float* __restrict__ cbias,
        const short* __restrict__ w2, const float* __restrict__ gbias,
        const short* __restrict__ hprev, short* __restrict__ hnext) {
    __shared__ uint4 Ld[3][68][9];       // 29376 B
    __shared__ short xch[64][68];        // 8704 B
    int tid = threadIdx.x;
    int wv = tid >> 6, l = tid & 63;
    int lr = l & 15, lg = l >> 4;
    int y = blockIdx.x >> 2;
    int x0 = (blockIdx.x & 3) << 6;

    for (int n = tid; n < 3 * 68 * 8; n += 256) {
        int r = n / (68 * 8);
        int rem = n - r * (68 * 8);
        int px = rem >> 3, e = rem & 7;
        const uint4* src = (const uint4*)(h1Tp +
            (((size_t)(y + 2 * r) * P2 + (x0 + px)) << 6)) + e;
        Ld[r][px][e] = *src;
    }
    __syncthreads();

    f32x4 C[4];
    #pragma unroll
    for (int nt = 0; nt < 4; ++nt) C[nt] = (f32x4){0.f, 0.f, 0.f, 0.f};

    #pragma unroll
    for (int tap = 0; tap < 9; ++tap) {
        int r = tap / 3;
        int dx = (tap % 3 - 1) * 2;
        const short* pA = wA + (size_t)(tap * 64 + wv * 16 + lr) * 64 + lg * 8;
        bf16x8 A0 = *(const bf16x8*)(pA);
        bf16x8 A1 = *(const bf16x8*)(pA + 32);
        #pragma unroll
        for (int nt = 0; nt < 4; ++nt) {
            int xl = nt * 16 + lr + dx + 2;
            bf16x8 B0 = *(const bf16x8*)&Ld[r][xl][lg];
            bf16x8 B1 = *(const bf16x8*)&Ld[r][xl][4 + lg];
            C[nt] = __builtin_amdgcn_mfma_f32_16x16x32_bf16(A0, B0, C[nt], 0, 0, 0);
            C[nt] = __builtin_amdgcn_mfma_f32_16x16x32_bf16(A1, B1, C[nt], 0, 0, 0);
        }
    }
    int co = wv * 16 + lg * 4;
    #pragma unroll
    for (int nt = 0; nt < 4; ++nt) {
        ushort4 st;
        st.x = (unsigned short)f2bf(fmaxf(C[nt][0] + cbias[co + 0], 0.f));
        st.y = (unsigned short)f2bf(fmaxf(C[nt][1] + cbias[co + 1], 0.f));
        st.z = (unsigned short)f2bf(fmaxf(C[nt][2] + cbias[co + 2], 0.f));
        st.w = (unsigned short)f2bf(fmaxf(C[nt][3] + cbias[co + 3], 0.f));
        *(ushort4*)&xch[nt * 16 + lr][co] = st;
    }
    __syncthreads();

    gru_tail<4, FIRST>(xch, hprev, w2, gbias, hnext, wv, lr, lg, y * 256 + x0);
}

// ===================== host orchestration =====================
extern "C" void kernel_launch(void* const* d_in, const int* in_sizes, int n_in,
                              void* d_out, int out_size, void* d_ws, size_t ws_size,
                              hipStream_t stream) {
    const c32* pred   = (const c32*)d_in[0];
    const c32* ksp    = (const c32*)d_in[1];
    const c32* sense  = (const c32*)d_in[2];
    const int* mask   = (const int*)d_in[3];
    const float* c1w  = (const float*)d_in[4];
    const float* c1b  = (const float*)d_in[5];
    const float* g1iw = (const float*)d_in[6];
    const float* g1ib = (const float*)d_in[7];
    const float* g1hw = (const float*)d_in[8];
    const float* g1hb = (const float*)d_in[9];
    const float* c2w  = (const float*)d_in[10];
    const float* c2b  = (const float*)d_in[11];
    const float* g2iw = (const float*)d_in[12];
    const float* g2ib = (const float*)d_in[13];
    const float* g2hw = (const float*)d_in[14];
    const float* g2hb = (const float*)d_in[15];
    const float* fw   = (const float*)d_in[16];
    const float* dcw  = (const float*)d_in[17];

    const size_t PP = (size_t)P2 * P2;     // 67600 padded pixels
    float* w0 = (float*)d_ws;
    c32* base = (c32*)w0;                  // NC*HW complex
    c32* tmp  = base + NC * HW;            // NC*HW complex (init only)
    c32* eta  = tmp + NC * HW;             // HW complex
    unsigned* Fkb = (unsigned*)(eta + HW); // NC*HW packed bf16 complex
    unsigned* senseb = Fkb + NC * HW;      // NC*HW packed bf16 complex
    short* gTp = (short*)(senseb + NC * HW); // PP*4 bf16 (padded)
    short* h1Ta = gTp + PP * 4;            // PP*64 bf16 (padded)
    short* h1Tb = h1Ta + PP * 64;
    short* h2Ta = h1Tb + PP * 64;
    short* h2Tb = h2Ta + PP * 64;
    short* w2a  = h2Tb + PP * 64;          // 256*128 bf16
    short* w2b  = w2a + 256 * 128;
    float* biasA = (float*)(w2b + 256 * 128);
    float* biasB = biasA + 256;
    short* wAc2 = (short*)(biasB + 256);   // 9*64*64 bf16
    short* wAc1 = wAc2 + 9 * 64 * 64;      // 64*128 bf16
    short* wAcf = wAc1 + 64 * 128;         // 9*16*64 bf16

    dim3 B(256);
    const int gCHW = NC * HW / 256;   // 3072
    const int gHW  = HW / 256;        // 256
    const int gROW = NC * 256 / 2;    // 1536 (2 rows/block)
    dim3 gCOL(32, NC);                // 8-col tiles, 1024 thr
    dim3 B1024(1024);
    dim3 B768(768);
    const int gC1 = HW / 32;          // 2048 blocks (conv1+gru1)
    const int gC2 = HW / 64;          // 1024 blocks (conv2+gru2)

    // border zeroing + weight/sense prep (once per call)
    k_zero_border<<<9, B, 0, stream>>>(gTp, h1Ta, h1Tb, h2Ta, h2Tb);
    k_prep_gru<<<256, 128, 0, stream>>>(g1iw, g1ib, g1hw, g1hb, w2a, biasA);
    k_prep_gru<<<256, 128, 0, stream>>>(g2iw, g2ib, g2hw, g2hb, w2b, biasB);
    k_prep_c2<<<144, 256, 0, stream>>>(c2w, wAc2);
    k_prep_c1<<<32, 256, 0, stream>>>(c1w, wAc1);
    k_prep_cf<<<36, 256, 0, stream>>>(fw, wAcf);
    k_prep_sense<<<gCHW, B, 0, stream>>>(sense, senseb);

    // eta0 = sum_c ifft2c(pred_c) * conj(sense_c)   (fp32 init path)
    fft_rows_pre<<<gROW, B, 0, stream>>>(tmp, pred);
    fft_cols<<<gCOL, B1024, 0, stream>>>(tmp, -1.0f);
    k_combine_eta0<<<gHW, B, 0, stream>>>(tmp, sense, eta);

    k_base<<<gCHW, B, 0, stream>>>(ksp, pred, mask, dcw, base);

    // F_0: forward FFT of S*(eta0*sense) -> packed Fk; fused epilogue -> residual
    fft_rows_exp<<<gROW, B, 0, stream>>>(Fkb, eta, sense);
    fft_cols_fused<<<gCOL, B1024, 0, stream>>>(Fkb, base, ksp, mask, (c32*)d_out, 0);

    short* h1c = h1Ta; short* h1n = h1Tb;
    short* h2c = h2Ta; short* h2n = h2Tb;
    c32* outp = (c32*)d_out;

    for (int t = 0; t < NT; ++t) {
        fft_rows_grad<<<gHW, B768, 0, stream>>>(Fkb, senseb, eta, gTp);

        if (t == 0) {
            conv1_gru1<true><<<gC1, B, 0, stream>>>(gTp, wAc1, c1b, w2a, biasA, h1c, h1n);
        } else {
            conv1_gru1<false><<<gC1, B, 0, stream>>>(gTp, wAc1, c1b, w2a, biasA, h1c, h1n);
        }
        { short* s = h1c; h1c = h1n; h1n = s; }
        if (t == 0) {
            conv2_gru2<true><<<gC2, B, 0, stream>>>(h1c, wAc2, c2b, w2b, biasB, h2c, h2n);
        } else {
            conv2_gru2<false><<<gC2, B, 0, stream>>>(h1c, wAc2, c2b, w2b, biasB, h2c, h2n);
        }
        { short* s = h2c; h2c = h2n; h2n = s; }

        // merged: final conv (eta += d) + forward row FFT -> packed Fk
        final_exp<<<gHW, B768, 0, stream>>>(h2c, wAcf, eta, senseb, Fkb);

        fft_cols_fused<<<gCOL, B1024, 0, stream>>>(Fkb, base, ksp, mask,
                                                   outp + (size_t)t * NC * HW, 1);
    }
}